// Round 19
// baseline (543.894 us; speedup 1.0000x reference)
//
#include <hip/hip_runtime.h>
#include <hip/hip_bf16.h>

#define BATCH 2048
#define FEAT  768
#define NIND  1024
#define NCLS  16

typedef unsigned short u16;
typedef __attribute__((ext_vector_type(8))) __bf16 bf16x8;
typedef __attribute__((ext_vector_type(4))) float f32x4;

static __device__ __forceinline__ unsigned f2bf(float f) {
  unsigned u = __float_as_uint(f);
  unsigned r = ((u >> 16) & 1u) + 0x7FFFu;
  return (u + r) >> 16;                       // RNE bf16 in low 16 bits
}
static __device__ __forceinline__ float bflo(unsigned x) {
  return __uint_as_float((x & 0xFFFFu) << 16);
}
static __device__ __forceinline__ float bfhi(unsigned x) {
  return __uint_as_float(x & 0xFFFF0000u);
}

// async 16B global->LDS (LDS dest = wave-uniform base + lane*16)
static __device__ __forceinline__ void gload16(const u16* g, u16* l) {
  __builtin_amdgcn_global_load_lds(
      (const __attribute__((address_space(1))) void*)g,
      (__attribute__((address_space(3))) void*)l, 16, 0, 0);
}

// pack 8 bf16 (as uint4) scaled by wv[0..7] back to 8 bf16 (uint4)
static __device__ __forceinline__ uint4 scale8(uint4 v, const float* wv) {
  unsigned out[4];
  const unsigned* in = (const unsigned*)&v;
  #pragma unroll
  for (int i = 0; i < 4; ++i) {
    float lo = bflo(in[i]) * wv[2*i];
    float hi = bfhi(in[i]) * wv[2*i+1];
    __hip_bfloat162 pk = __float22bfloat162_rn(float2{lo, hi});
    out[i] = *(unsigned*)&pk;
  }
  return uint4{out[0], out[1], out[2], out[3]};
}

// K0a: xB = bf16(x), elementwise
__global__ __launch_bounds__(256) void xcast_kernel(
    const float* __restrict__ x, u16* __restrict__ xB)
{
  size_t f = ((size_t)blockIdx.x * 256 + threadIdx.x) * 8;
  float4 a = *(const float4*)(x + f);
  float4 b = *(const float4*)(x + f + 4);
  uint4 o;
  o.x = (f2bf(a.x) & 0xFFFFu) | (f2bf(a.y) << 16);
  o.y = (f2bf(a.z) & 0xFFFFu) | (f2bf(a.w) << 16);
  o.z = (f2bf(b.x) & 0xFFFFu) | (f2bf(b.y) << 16);
  o.w = (f2bf(b.z) & 0xFFFFu) | (f2bf(b.w) << 16);
  *(uint4*)(xB + f) = o;
}

// K0b: rwT[i][k] = bf16(rw[k][i])  (LDS-tiled transpose)
__global__ __launch_bounds__(256) void rwt_kernel(
    const float* __restrict__ rw, u16* __restrict__ rwT)
{
  __shared__ float ts[64][65];
  const int k0 = blockIdx.x * 64, i0 = blockIdx.y * 64;
  const int tid = threadIdx.x;
  #pragma unroll
  for (int t = 0; t < 4; ++t) {
    int f = t * 256 + tid;
    int r = f >> 4, c4 = (f & 15) << 2;
    *(float4*)(&ts[r][c4]) = *(const float4*)(rw + (size_t)(k0 + r) * NIND + i0 + c4);
  }
  __syncthreads();
  #pragma unroll
  for (int t = 0; t < 4; ++t) {
    int f = t * 256 + tid;
    int r = f >> 4, c4 = (f & 15) << 2;   // r = i-local, c4 = k-local base
    uint2 o;
    o.x = (f2bf(ts[c4+0][r]) & 0xFFFFu) | (f2bf(ts[c4+1][r]) << 16);
    o.y = (f2bf(ts[c4+2][r]) & 0xFFFFu) | (f2bf(ts[c4+3][r]) << 16);
    *(uint2*)(rwT + (size_t)(i0 + r) * FEAT + k0 + c4) = o;
  }
}

// K1: MFMA phi. phiB[b][i], phiTB[i][b] = bf16(SC*cos(2*(x@W+b))). K=768.
__global__ __launch_bounds__(256) void phimm_kernel(
    const u16* __restrict__ xB, const u16* __restrict__ rwT,
    const float* __restrict__ rb, u16* __restrict__ phiB,
    u16* __restrict__ phiTB)
{
  __shared__ u16 sh[128 * 128];      // staging (2x 128x64) then transpose tile
  u16* Als = sh;
  u16* Bls = sh + 8192;
  const int b0 = blockIdx.x * 128, i0 = blockIdx.y * 128;
  const int tid = threadIdx.x;
  const int wid = tid >> 6, lane = tid & 63;
  const int wr = wid >> 1, wc = wid & 1;
  const u16* Ag = xB + (size_t)b0 * FEAT;
  const u16* Bg = rwT + (size_t)i0 * FEAT;
  f32x4 acc[4][4];
  #pragma unroll
  for (int m = 0; m < 4; ++m)
    #pragma unroll
    for (int n = 0; n < 4; ++n) acc[m][n] = (f32x4){0.f, 0.f, 0.f, 0.f};
  for (int kb = 0; kb < FEAT; kb += 64) {
    #pragma unroll
    for (int c = 0; c < 4; ++c) {
      int f = c * 256 + tid;
      int row = f >> 3, s = f & 7;
      int sc = (s ^ (row & 7)) << 3;
      gload16(Ag + (size_t)row * FEAT + kb + sc, Als + ((c * 256 + wid * 64) << 3));
      gload16(Bg + (size_t)row * FEAT + kb + sc, Bls + ((c * 256 + wid * 64) << 3));
    }
    __syncthreads();
    #pragma unroll
    for (int ks = 0; ks < 2; ++ks) {
      bf16x8 af[4], bfr[4];
      #pragma unroll
      for (int m = 0; m < 4; ++m) {
        int row = wr * 64 + m * 16 + (lane & 15);
        int kq = ks * 32 + (lane >> 4) * 8;
        int idx = (row * 64 + kq) ^ ((row & 7) << 3);
        af[m] = *(const bf16x8*)(&Als[idx]);
      }
      #pragma unroll
      for (int n = 0; n < 4; ++n) {
        int row = wc * 64 + n * 16 + (lane & 15);
        int kq = ks * 32 + (lane >> 4) * 8;
        int idx = (row * 64 + kq) ^ ((row & 7) << 3);
        bfr[n] = *(const bf16x8*)(&Bls[idx]);
      }
      #pragma unroll
      for (int m = 0; m < 4; ++m)
        #pragma unroll
        for (int n = 0; n < 4; ++n)
          acc[m][n] = __builtin_amdgcn_mfma_f32_16x16x32_bf16(af[m], bfr[n], acc[m][n], 0, 0, 0);
    }
    __syncthreads();
  }
  const float SC = 0.04419417382415922f;   // sqrt(2/1024)
  float rbl[4];
  #pragma unroll
  for (int n = 0; n < 4; ++n) rbl[n] = rb[i0 + wc * 64 + n * 16 + (lane & 15)];
  #pragma unroll
  for (int m = 0; m < 4; ++m) {
    #pragma unroll
    for (int n = 0; n < 4; ++n) {
      #pragma unroll
      for (int r = 0; r < 4; ++r) {
        int lb = wr * 64 + m * 16 + (lane >> 4) * 4 + r;
        int li = wc * 64 + n * 16 + (lane & 15);
        float proj = 2.0f * (acc[m][n][r] + rbl[n]);
        u16 bv = (u16)f2bf(SC * cosf(proj));
        phiB[(size_t)(b0 + lb) * NIND + i0 + li] = bv;
        int idx = (li * 128 + lb) ^ ((li & 7) << 3);
        sh[idx] = bv;
      }
    }
  }
  __syncthreads();
  #pragma unroll
  for (int t = 0; t < 8; ++t) {
    int f = t * 256 + tid;             // 2048 uint4-slots over 128x128 u16
    int li = f >> 4, c8 = (f & 15) << 3;
    int idx = (li * 128 + c8) ^ ((li & 7) << 3);
    uint4 v = *(const uint4*)(&sh[idx]);
    *(uint4*)(phiTB + (size_t)(i0 + li) * BATCH + b0 + c8) = v;
  }
}

// K2: logits from phiB (bf16), 16 batch rows per block, thread = (row, class)
__global__ __launch_bounds__(256) void logits_kernel(
    const u16* __restrict__ phiB, const float* __restrict__ bw,
    const float* __restrict__ bbias, float* __restrict__ out,
    float* __restrict__ wmat)
{
  __shared__ float ph[16][132];
  __shared__ float bwl[16][132];
  __shared__ float lg[16][17];
  const int b0 = blockIdx.x * 16;
  const int tid = threadIdx.x;
  const int bl = tid & 15, kq = tid >> 4;
  float acc = 0.f;
  for (int kb = 0; kb < NIND; kb += 128) {
    {
      int row = tid >> 4, c8 = (tid & 15) << 3;
      uint4 v = *(const uint4*)(phiB + (size_t)(b0 + row) * NIND + kb + c8);
      const unsigned* u = (const unsigned*)&v;
      #pragma unroll
      for (int j = 0; j < 4; ++j) {
        ph[row][c8 + 2*j]     = bflo(u[j]);
        ph[row][c8 + 2*j + 1] = bfhi(u[j]);
      }
    }
    #pragma unroll
    for (int t = 0; t < 2; ++t) {
      int f = t * 256 + tid;
      int row = f >> 5, c4 = (f & 31) << 2;
      *(float4*)(&bwl[row][c4]) = *(const float4*)(bw + (size_t)row * NIND + kb + c4);
    }
    __syncthreads();
    #pragma unroll 8
    for (int q = 0; q < 128; q += 4) {
      float4 a = *(const float4*)(&ph[bl][q]);
      float4 b4 = *(const float4*)(&bwl[kq][q]);
      acc += a.x*b4.x + a.y*b4.y + a.z*b4.z + a.w*b4.w;
    }
    __syncthreads();
  }
  float v = acc + bbias[kq];
  lg[bl][kq] = v;
  out[(size_t)(b0 + bl) * NCLS + kq] = v;
  __syncthreads();
  if (tid < 16) {
    float mx = -1e30f;
    #pragma unroll
    for (int k = 0; k < 16; ++k) mx = fmaxf(mx, lg[tid][k]);
    float s = 0.f, ex[16];
    #pragma unroll
    for (int k = 0; k < 16; ++k) { ex[k] = expf(lg[tid][k] - mx); s += ex[k]; }
    float inv = 1.0f / s;
    #pragma unroll
    for (int k = 0; k < 16; ++k) {
      float p = ex[k] * inv;
      wmat[(size_t)k * BATCH + b0 + tid] = p * (1.0f - p);
    }
  }
}

// K2b: phiW[k][i][b] = bf16(wmat[k][b] * phi[i][b])  (from bf16 phiTB)
__global__ __launch_bounds__(256) void scalew_kernel(
    const u16* __restrict__ phiTB, const float* __restrict__ wmat,
    u16* __restrict__ phiW)
{
  const int k = blockIdx.y;
  size_t flat = ((size_t)blockIdx.x * 256 + threadIdx.x) * 8;
  int b = (int)(flat & 2047);
  uint4 pv = *(const uint4*)(phiTB + flat);
  float4 w0 = *(const float4*)(wmat + (size_t)k * BATCH + b);
  float4 w1 = *(const float4*)(wmat + (size_t)k * BATCH + b + 4);
  float wv[8] = {w0.x, w0.y, w0.z, w0.w, w1.x, w1.y, w1.z, w1.w};
  *(uint4*)(phiW + (size_t)k * NIND * BATCH + flat) = scale8(pv, wv);
}

// K3: MFMA bf16 gram -> Pb bf16. FULL 64-tile grid (4 blocks/CU hides the
// 2-barrier-per-K-step latency; R17-verified). XCD = ti.
__global__ __launch_bounds__(256) void gram_kernel(
    const u16* __restrict__ phiW, const u16* __restrict__ phiTB,
    const float* __restrict__ prec, u16* __restrict__ Pb)
{
  __shared__ u16 Als[128 * 64];
  __shared__ u16 Bls[128 * 64];
  const int ti = blockIdx.x & 7, tj = blockIdx.x >> 3;   // XCD = ti
  const int k = blockIdx.y;
  const int i0 = ti * 128, j0 = tj * 128;
  const int tid = threadIdx.x;
  const int wid = tid >> 6, lane = tid & 63;
  const int wr = wid >> 1, wc = wid & 1;
  const u16* Ag = phiW + (size_t)k * NIND * BATCH + (size_t)i0 * BATCH;
  const u16* Bg = phiTB + (size_t)j0 * BATCH;
  f32x4 acc[4][4];
  #pragma unroll
  for (int m = 0; m < 4; ++m)
    #pragma unroll
    for (int n = 0; n < 4; ++n) acc[m][n] = (f32x4){0.f, 0.f, 0.f, 0.f};
  for (int b0 = 0; b0 < BATCH; b0 += 64) {
    #pragma unroll
    for (int c = 0; c < 4; ++c) {
      int f = c * 256 + tid;
      int row = f >> 3, s = f & 7;
      int sc = (s ^ (row & 7)) << 3;
      gload16(Ag + (size_t)row * BATCH + b0 + sc, Als + ((c * 256 + wid * 64) << 3));
      gload16(Bg + (size_t)row * BATCH + b0 + sc, Bls + ((c * 256 + wid * 64) << 3));
    }
    __syncthreads();
    #pragma unroll
    for (int ks = 0; ks < 2; ++ks) {
      bf16x8 af[4], bfr[4];
      #pragma unroll
      for (int m = 0; m < 4; ++m) {
        int row = wr * 64 + m * 16 + (lane & 15);
        int kb = ks * 32 + (lane >> 4) * 8;
        int idx = (row * 64 + kb) ^ ((row & 7) << 3);
        af[m] = *(const bf16x8*)(&Als[idx]);
      }
      #pragma unroll
      for (int n = 0; n < 4; ++n) {
        int row = wc * 64 + n * 16 + (lane & 15);
        int kb = ks * 32 + (lane >> 4) * 8;
        int idx = (row * 64 + kb) ^ ((row & 7) << 3);
        bfr[n] = *(const bf16x8*)(&Bls[idx]);
      }
      #pragma unroll
      for (int m = 0; m < 4; ++m)
        #pragma unroll
        for (int n = 0; n < 4; ++n)
          acc[m][n] = __builtin_amdgcn_mfma_f32_16x16x32_bf16(af[m], bfr[n], acc[m][n], 0, 0, 0);
    }
    __syncthreads();
  }
  const size_t kb2 = (size_t)k * NIND * NIND;
  #pragma unroll
  for (int m = 0; m < 4; ++m) {
    #pragma unroll
    for (int n = 0; n < 4; ++n) {
      #pragma unroll
      for (int r = 0; r < 4; ++r) {
        int gi = i0 + wr * 64 + m * 16 + (lane >> 4) * 4 + r;
        int gj = j0 + wc * 64 + n * 16 + (lane & 15);
        size_t idx = kb2 + (size_t)gi * NIND + gj;
        float v = acc[m][n][r] + prec[idx];
        Pb[idx] = (u16)f2bf(v);
      }
    }
  }
}

// K4: Gershgorin bound per class: gmax[k] = max_i sum_j |P_ij| (certified >= lambda_max)
__global__ __launch_bounds__(256) void gersh_kernel(
    const u16* __restrict__ Pb, unsigned* __restrict__ gmax)
{
  __shared__ float psum[64][17];
  const int k = blockIdx.y, rbk = blockIdx.x;
  const int tid = threadIdx.x;
  const size_t mb = (size_t)k * NIND * NIND;
  #pragma unroll
  for (int p = 0; p < 4; ++p) {
    int rl = p * 16 + (tid >> 4);
    int row = rbk * 64 + rl;
    int ch = tid & 15;
    float s = 0.f;
    const u16* base = Pb + mb + (size_t)row * NIND + ch * 64;
    #pragma unroll
    for (int c8 = 0; c8 < 8; ++c8) {
      uint4 u = *(const uint4*)(base + c8 * 8);
      const unsigned* uu = (const unsigned*)&u;
      #pragma unroll
      for (int q = 0; q < 4; ++q)
        s += fabsf(bflo(uu[q])) + fabsf(bfhi(uu[q]));
    }
    psum[rl][ch] = s;
  }
  __syncthreads();
  if (tid < 64) {
    float s = 0.f;
    #pragma unroll
    for (int j = 0; j < 16; ++j) s += psum[tid][j];
    psum[tid][16] = s;
  }
  __syncthreads();
  if (tid == 0) {
    float mx = 0.f;
    for (int t = 0; t < 64; ++t) mx = fmaxf(mx, psum[t][16]);
    atomicMax(gmax + k, __float_as_uint(mx));
  }
}

// K6: GEMM C = A (*) B^T with epilogue modes. Full 64 tiles, XCD swizzle.
// mode 0: C = acc
// mode 1: C = 2*Xadd - acc                      (Newton second half)
// mode 2: C = a3*acc + a2*Xadd + a1*Pex + a0*I  (deg-3 Chebyshev init, R13-validated)
// mode 3: mode 1, then double entries whose 128-tiles differ (pre-weights M for
//         the triangular-K quadratic form in vgemm; phi^T M phi only sees sym(M))
__global__ __launch_bounds__(256) void ntgemm_kernel(
    const u16* __restrict__ A, const u16* __restrict__ B,
    const u16* __restrict__ Xadd, const u16* __restrict__ Pex,
    const unsigned* __restrict__ gmax, u16* __restrict__ C, int mode)
{
  __shared__ u16 Als[128 * 64];
  __shared__ u16 Bls[128 * 64];
  const int k = blockIdx.y;
  const int ti = blockIdx.x & 7, tj = blockIdx.x >> 3;   // XCD swizzle (T1)
  const int i0 = ti * 128, j0 = tj * 128;
  const int tid = threadIdx.x;
  const int wid = tid >> 6, lane = tid & 63;
  const int wr = wid >> 1, wc = wid & 1;
  const size_t mb = (size_t)k * NIND * NIND;
  const u16* Ag = A + mb + (size_t)i0 * NIND;
  const u16* Bg = B + mb + (size_t)j0 * NIND;
  f32x4 acc[4][4];
  #pragma unroll
  for (int m = 0; m < 4; ++m)
    #pragma unroll
    for (int n = 0; n < 4; ++n) acc[m][n] = (f32x4){0.f, 0.f, 0.f, 0.f};
  for (int kb = 0; kb < NIND; kb += 64) {
    #pragma unroll
    for (int c = 0; c < 4; ++c) {
      int f = c * 256 + tid;
      int row = f >> 3, s = f & 7;
      int sc = (s ^ (row & 7)) << 3;
      gload16(Ag + (size_t)row * NIND + kb + sc, Als + ((c * 256 + wid * 64) << 3));
      gload16(Bg + (size_t)row * NIND + kb + sc, Bls + ((c * 256 + wid * 64) << 3));
    }
    __syncthreads();
    #pragma unroll
    for (int ks = 0; ks < 2; ++ks) {
      bf16x8 af[4], bfr[4];
      #pragma unroll
      for (int m = 0; m < 4; ++m) {
        int row = wr * 64 + m * 16 + (lane & 15);
        int kq = ks * 32 + (lane >> 4) * 8;
        int idx = (row * 64 + kq) ^ ((row & 7) << 3);
        af[m] = *(const bf16x8*)(&Als[idx]);
      }
      #pragma unroll
      for (int n = 0; n < 4; ++n) {
        int row = wc * 64 + n * 16 + (lane & 15);
        int kq = ks * 32 + (lane >> 4) * 8;
        int idx = (row * 64 + kq) ^ ((row & 7) << 3);
        bfr[n] = *(const bf16x8*)(&Bls[idx]);
      }
      #pragma unroll
      for (int m = 0; m < 4; ++m)
        #pragma unroll
        for (int n = 0; n < 4; ++n)
          acc[m][n] = __builtin_amdgcn_mfma_f32_16x16x32_bf16(af[m], bfr[n], acc[m][n], 0, 0, 0);
    }
    __syncthreads();
  }
  float a0 = 0.f, a1 = 0.f, a2 = 0.f, a3 = 0.f;
  if (mode == 2) {
    float G = __uint_as_float(gmax[k]) * 1.001f + 0.01f;
    if (G < 1.05f) G = 1.05f;
    float s = 1.0f + G, dd = G - 1.0f;
    float s2 = s * s, d2 = dd * dd;
    float D = 8.0f * s2 * s2 - 8.0f * d2 * s2 + d2 * d2;
    a3 = -128.0f / D;
    a2 = 256.0f * s / D;
    a1 = -(192.0f * s2 - 32.0f * d2) / D;
    a0 = (64.0f * s2 * s - 32.0f * d2 * s) / D;
  }
  #pragma unroll
  for (int m = 0; m < 4; ++m) {
    #pragma unroll
    for (int n = 0; n < 4; ++n) {
      #pragma unroll
      for (int r = 0; r < 4; ++r) {
        int gi = i0 + wr * 64 + m * 16 + (lane >> 4) * 4 + r;
        int gj = j0 + wc * 64 + n * 16 + (lane & 15);
        size_t idx = mb + (size_t)gi * NIND + gj;
        float v = acc[m][n][r];
        if (mode == 1 || mode == 3) {
          v = 2.0f * bflo((unsigned)Xadd[idx]) - v;
          if (mode == 3 && ti != tj) v *= 2.0f;
        } else if (mode == 2) {
          v = a3 * v + a2 * bflo((unsigned)Xadd[idx]) + a1 * bflo((unsigned)Pex[idx]);
          if (gi == gj) v += a0;
        }
        C[idx] = (u16)f2bf(v);
      }
    }
  }
}

// K7: variance GEMM, triangular K: M has tile-off-diag pre-doubled (mode 3),
// so var_b = sum_{It} phi[It]^T Mw[It, Jt>=It] phi[Jt] with K from It*128.
__global__ __launch_bounds__(256) void vgemm_kernel(
    const u16* __restrict__ phiB, const u16* __restrict__ M,
    float* __restrict__ partial)
{
  __shared__ u16 Als[128 * 64];
  __shared__ u16 Bls[128 * 64];
  __shared__ float red[128][33];
  const int btile = blockIdx.x >> 3, It = blockIdx.x & 7;
  const int k = blockIdx.y;
  const int b0 = btile * 128, i0 = It * 128;
  const int tid = threadIdx.x;
  const int wid = tid >> 6, lane = tid & 63;
  const int wr = wid >> 1, wc = wid & 1;
  const int q = lane >> 4, l15 = lane & 15;
  const u16* Ag = phiB + (size_t)b0 * NIND;
  const u16* Bg = M + (size_t)k * NIND * NIND + (size_t)i0 * NIND;
  f32x4 acc[4][4];
  #pragma unroll
  for (int m = 0; m < 4; ++m)
    #pragma unroll
    for (int n = 0; n < 4; ++n) acc[m][n] = (f32x4){0.f, 0.f, 0.f, 0.f};
  for (int kb = i0; kb < NIND; kb += 64) {
    #pragma unroll
    for (int c = 0; c < 4; ++c) {
      int f = c * 256 + tid;
      int row = f >> 3, s = f & 7;
      int sc = (s ^ (row & 7)) << 3;
      gload16(Ag + (size_t)row * NIND + kb + sc, Als + ((c * 256 + wid * 64) << 3));
      gload16(Bg + (size_t)row * NIND + kb + sc, Bls + ((c * 256 + wid * 64) << 3));
    }
    __syncthreads();
    #pragma unroll
    for (int ks = 0; ks < 2; ++ks) {
      bf16x8 af[4], bfr[4];
      #pragma unroll
      for (int m = 0; m < 4; ++m) {
        int row = wr * 64 + m * 16 + l15;
        int kq = ks * 32 + q * 8;
        int idx = (row * 64 + kq) ^ ((row & 7) << 3);
        af[m] = *(const bf16x8*)(&Als[idx]);
      }
      #pragma unroll
      for (int n = 0; n < 4; ++n) {
        int row = wc * 64 + n * 16 + l15;
        int kq = ks * 32 + q * 8;
        int idx = (row * 64 + kq) ^ ((row & 7) << 3);
        bfr[n] = *(const bf16x8*)(&Bls[idx]);
      }
      #pragma unroll
      for (int m = 0; m < 4; ++m)
        #pragma unroll
        for (int n = 0; n < 4; ++n)
          acc[m][n] = __builtin_amdgcn_mfma_f32_16x16x32_bf16(af[m], bfr[n], acc[m][n], 0, 0, 0);
    }
    __syncthreads();
  }
  float vs[4][4] = {};
  #pragma unroll
  for (int m = 0; m < 4; ++m) {
    #pragma unroll
    for (int r = 0; r < 4; ++r) {
      int gb = b0 + wr * 64 + m * 16 + q * 4 + r;
      #pragma unroll
      for (int n = 0; n < 4; ++n) {
        int gi = i0 + wc * 64 + n * 16 + l15;
        float pv = bflo((unsigned)phiB[(size_t)gb * NIND + gi]);
        vs[m][r] += acc[m][n][r] * pv;
      }
    }
  }
  #pragma unroll
  for (int m = 0; m < 4; ++m)
    #pragma unroll
    for (int r = 0; r < 4; ++r)
      red[wr * 64 + m * 16 + q * 4 + r][wc * 16 + l15] = vs[m][r];
  __syncthreads();
  if (tid < 128) {
    float s = 0.f;
    #pragma unroll
    for (int t = 0; t < 32; ++t) s += red[tid][t];
    partial[((size_t)It * NCLS + k) * BATCH + b0 + tid] = s;
  }
}

// K8: out variances[b][k] = sum_It partial[It][k][b]
__global__ __launch_bounds__(256) void reduce_kernel(
    const float* __restrict__ partial, float* __restrict__ out)
{
  int t = blockIdx.x * 256 + threadIdx.x;
  int k = t >> 11, b = t & 2047;
  float s = 0.f;
  #pragma unroll
  for (int It = 0; It < 8; ++It)
    s += partial[((size_t)It * NCLS + k) * BATCH + b];
  out[(size_t)BATCH * NCLS + (size_t)b * NCLS + k] = s;
}

extern "C" void kernel_launch(void* const* d_in, const int* in_sizes, int n_in,
                              void* d_out, int out_size, void* d_ws, size_t ws_size,
                              hipStream_t stream)
{
  (void)in_sizes; (void)n_in; (void)ws_size; (void)out_size;
  const float* x   = (const float*)d_in[0];
  const float* rw  = (const float*)d_in[1];
  const float* rb  = (const float*)d_in[2];
  const float* bw  = (const float*)d_in[3];
  const float* bb  = (const float*)d_in[4];
  const float* prc = (const float*)d_in[5];
  float* out = (float*)d_out;
  char* ws = (char*)d_ws;
  size_t off = 0;
  auto alloc = [&](size_t bytes) -> void* {
    void* p = ws + off;
    off = (off + bytes + 255) & ~(size_t)255;
    return p;
  };
  const size_t MSZ = (size_t)NCLS * NIND * NIND * 2;   // 32MB bf16 matrix
  u16*   xB     = (u16*)  alloc((size_t)BATCH * FEAT * 2);
  u16*   rwT    = (u16*)  alloc((size_t)NIND * FEAT * 2);
  u16*   phiB   = (u16*)  alloc((size_t)BATCH * NIND * 2);
  u16*   phiTB  = (u16*)  alloc((size_t)NIND * BATCH * 2);
  float* wmat   = (float*)alloc((size_t)NCLS * BATCH * 4);
  u16*   Pb     = (u16*)  alloc(MSZ);
  unsigned* gbound = (unsigned*)alloc((size_t)NCLS * 4);
  float* partial = (float*)alloc((size_t)8 * NCLS * BATCH * 4);
  u16*   Xa     = (u16*)alloc(MSZ);
  u16*   B2     = (u16*)alloc(MSZ);
  u16*   BY     = (u16*)alloc(MSZ);
  // phiW (64MB) aliases Xa+B2 (contiguous): dead before G2 writes Xa.
  u16*   phiW   = Xa;

  hipMemsetAsync(gbound, 0, (size_t)NCLS * 4, stream);
  xcast_kernel<<<dim3(BATCH * FEAT / 2048), 256, 0, stream>>>(x, xB);
  rwt_kernel<<<dim3(FEAT / 64, NIND / 64), 256, 0, stream>>>(rw, rwT);
  phimm_kernel<<<dim3(BATCH / 128, NIND / 128), 256, 0, stream>>>(xB, rwT, rb, phiB, phiTB);
  logits_kernel<<<dim3(BATCH / 16), 256, 0, stream>>>(phiB, bw, bb, out, wmat);
  scalew_kernel<<<dim3(1024, NCLS), 256, 0, stream>>>(phiTB, wmat, phiW);
  gram_kernel<<<dim3(64, NCLS), 256, 0, stream>>>(phiW, phiTB, prc, Pb);
  gersh_kernel<<<dim3(16, NCLS), 256, 0, stream>>>(Pb, gbound);
  const dim3 gg(64, NCLS);
  // G1: BY = P^2
  ntgemm_kernel<<<gg, 256, 0, stream>>>(Pb, Pb, (u16*)nullptr, (u16*)nullptr,
                                        (unsigned*)nullptr, BY, 0);
  // G2: Xa = a3*P^3 + a2*P^2 + a1*P + a0*I  (cheb-3 fused into the P^3 GEMM)
  ntgemm_kernel<<<gg, 256, 0, stream>>>(BY, Pb, BY, Pb, gbound, Xa, 2);
  // G3+G4: one Newton iteration: BY = Xa*P ; B2 = (2*Xa - Xa*BY^T) with
  // tile-off-diagonal entries doubled (mode 3) for the triangular vgemm.
  ntgemm_kernel<<<gg, 256, 0, stream>>>(Xa, Pb, (u16*)nullptr, (u16*)nullptr,
                                        (unsigned*)nullptr, BY, 0);
  ntgemm_kernel<<<gg, 256, 0, stream>>>(Xa, BY, Xa, (u16*)nullptr,
                                        (unsigned*)nullptr, B2, 3);
  // variances: var_b = phi^T sym(M) phi via triangular K
  vgemm_kernel<<<dim3(128, NCLS), 256, 0, stream>>>(phiB, B2, partial);
  reduce_kernel<<<dim3(128), 256, 0, stream>>>(partial, out);
}

// Round 20
// 518.462 us; speedup vs baseline: 1.0491x; 1.0491x over previous
//
#include <hip/hip_runtime.h>
#include <hip/hip_bf16.h>

#define BATCH 2048
#define FEAT  768
#define NIND  1024
#define NCLS  16

typedef unsigned short u16;
typedef __attribute__((ext_vector_type(8))) __bf16 bf16x8;
typedef __attribute__((ext_vector_type(4))) float f32x4;

static __device__ __forceinline__ unsigned f2bf(float f) {
  unsigned u = __float_as_uint(f);
  unsigned r = ((u >> 16) & 1u) + 0x7FFFu;
  return (u + r) >> 16;                       // RNE bf16 in low 16 bits
}
static __device__ __forceinline__ float bflo(unsigned x) {
  return __uint_as_float((x & 0xFFFFu) << 16);
}
static __device__ __forceinline__ float bfhi(unsigned x) {
  return __uint_as_float(x & 0xFFFF0000u);
}

// async 16B global->LDS (LDS dest = wave-uniform base + lane*16)
static __device__ __forceinline__ void gload16(const u16* g, u16* l) {
  __builtin_amdgcn_global_load_lds(
      (const __attribute__((address_space(1))) void*)g,
      (__attribute__((address_space(3))) void*)l, 16, 0, 0);
}

// pack 8 bf16 (as uint4) scaled by wv[0..7] back to 8 bf16 (uint4)
static __device__ __forceinline__ uint4 scale8(uint4 v, const float* wv) {
  unsigned out[4];
  const unsigned* in = (const unsigned*)&v;
  #pragma unroll
  for (int i = 0; i < 4; ++i) {
    float lo = bflo(in[i]) * wv[2*i];
    float hi = bfhi(in[i]) * wv[2*i+1];
    __hip_bfloat162 pk = __float22bfloat162_rn(float2{lo, hi});
    out[i] = *(unsigned*)&pk;
  }
  return uint4{out[0], out[1], out[2], out[3]};
}

// K0a: xB = bf16(x), elementwise
__global__ __launch_bounds__(256) void xcast_kernel(
    const float* __restrict__ x, u16* __restrict__ xB)
{
  size_t f = ((size_t)blockIdx.x * 256 + threadIdx.x) * 8;
  float4 a = *(const float4*)(x + f);
  float4 b = *(const float4*)(x + f + 4);
  uint4 o;
  o.x = (f2bf(a.x) & 0xFFFFu) | (f2bf(a.y) << 16);
  o.y = (f2bf(a.z) & 0xFFFFu) | (f2bf(a.w) << 16);
  o.z = (f2bf(b.x) & 0xFFFFu) | (f2bf(b.y) << 16);
  o.w = (f2bf(b.z) & 0xFFFFu) | (f2bf(b.w) << 16);
  *(uint4*)(xB + f) = o;
}

// K0b: rwT[i][k] = bf16(rw[k][i])  (LDS-tiled transpose)
__global__ __launch_bounds__(256) void rwt_kernel(
    const float* __restrict__ rw, u16* __restrict__ rwT)
{
  __shared__ float ts[64][65];
  const int k0 = blockIdx.x * 64, i0 = blockIdx.y * 64;
  const int tid = threadIdx.x;
  #pragma unroll
  for (int t = 0; t < 4; ++t) {
    int f = t * 256 + tid;
    int r = f >> 4, c4 = (f & 15) << 2;
    *(float4*)(&ts[r][c4]) = *(const float4*)(rw + (size_t)(k0 + r) * NIND + i0 + c4);
  }
  __syncthreads();
  #pragma unroll
  for (int t = 0; t < 4; ++t) {
    int f = t * 256 + tid;
    int r = f >> 4, c4 = (f & 15) << 2;   // r = i-local, c4 = k-local base
    uint2 o;
    o.x = (f2bf(ts[c4+0][r]) & 0xFFFFu) | (f2bf(ts[c4+1][r]) << 16);
    o.y = (f2bf(ts[c4+2][r]) & 0xFFFFu) | (f2bf(ts[c4+3][r]) << 16);
    *(uint2*)(rwT + (size_t)(i0 + r) * FEAT + k0 + c4) = o;
  }
}

// K1: MFMA phi. phiB[b][i], phiTB[i][b] = bf16(SC*cos(2*(x@W+b))). K=768.
__global__ __launch_bounds__(256) void phimm_kernel(
    const u16* __restrict__ xB, const u16* __restrict__ rwT,
    const float* __restrict__ rb, u16* __restrict__ phiB,
    u16* __restrict__ phiTB)
{
  __shared__ u16 sh[128 * 128];      // staging (2x 128x64) then transpose tile
  u16* Als = sh;
  u16* Bls = sh + 8192;
  const int b0 = blockIdx.x * 128, i0 = blockIdx.y * 128;
  const int tid = threadIdx.x;
  const int wid = tid >> 6, lane = tid & 63;
  const int wr = wid >> 1, wc = wid & 1;
  const u16* Ag = xB + (size_t)b0 * FEAT;
  const u16* Bg = rwT + (size_t)i0 * FEAT;
  f32x4 acc[4][4];
  #pragma unroll
  for (int m = 0; m < 4; ++m)
    #pragma unroll
    for (int n = 0; n < 4; ++n) acc[m][n] = (f32x4){0.f, 0.f, 0.f, 0.f};
  for (int kb = 0; kb < FEAT; kb += 64) {
    #pragma unroll
    for (int c = 0; c < 4; ++c) {
      int f = c * 256 + tid;
      int row = f >> 3, s = f & 7;
      int sc = (s ^ (row & 7)) << 3;
      gload16(Ag + (size_t)row * FEAT + kb + sc, Als + ((c * 256 + wid * 64) << 3));
      gload16(Bg + (size_t)row * FEAT + kb + sc, Bls + ((c * 256 + wid * 64) << 3));
    }
    __syncthreads();
    #pragma unroll
    for (int ks = 0; ks < 2; ++ks) {
      bf16x8 af[4], bfr[4];
      #pragma unroll
      for (int m = 0; m < 4; ++m) {
        int row = wr * 64 + m * 16 + (lane & 15);
        int kq = ks * 32 + (lane >> 4) * 8;
        int idx = (row * 64 + kq) ^ ((row & 7) << 3);
        af[m] = *(const bf16x8*)(&Als[idx]);
      }
      #pragma unroll
      for (int n = 0; n < 4; ++n) {
        int row = wc * 64 + n * 16 + (lane & 15);
        int kq = ks * 32 + (lane >> 4) * 8;
        int idx = (row * 64 + kq) ^ ((row & 7) << 3);
        bfr[n] = *(const bf16x8*)(&Bls[idx]);
      }
      #pragma unroll
      for (int m = 0; m < 4; ++m)
        #pragma unroll
        for (int n = 0; n < 4; ++n)
          acc[m][n] = __builtin_amdgcn_mfma_f32_16x16x32_bf16(af[m], bfr[n], acc[m][n], 0, 0, 0);
    }
    __syncthreads();
  }
  const float SC = 0.04419417382415922f;   // sqrt(2/1024)
  float rbl[4];
  #pragma unroll
  for (int n = 0; n < 4; ++n) rbl[n] = rb[i0 + wc * 64 + n * 16 + (lane & 15)];
  #pragma unroll
  for (int m = 0; m < 4; ++m) {
    #pragma unroll
    for (int n = 0; n < 4; ++n) {
      #pragma unroll
      for (int r = 0; r < 4; ++r) {
        int lb = wr * 64 + m * 16 + (lane >> 4) * 4 + r;
        int li = wc * 64 + n * 16 + (lane & 15);
        float proj = 2.0f * (acc[m][n][r] + rbl[n]);
        u16 bv = (u16)f2bf(SC * cosf(proj));
        phiB[(size_t)(b0 + lb) * NIND + i0 + li] = bv;
        int idx = (li * 128 + lb) ^ ((li & 7) << 3);
        sh[idx] = bv;
      }
    }
  }
  __syncthreads();
  #pragma unroll
  for (int t = 0; t < 8; ++t) {
    int f = t * 256 + tid;             // 2048 uint4-slots over 128x128 u16
    int li = f >> 4, c8 = (f & 15) << 3;
    int idx = (li * 128 + c8) ^ ((li & 7) << 3);
    uint4 v = *(const uint4*)(&sh[idx]);
    *(uint4*)(phiTB + (size_t)(i0 + li) * BATCH + b0 + c8) = v;
  }
}

// K2: logits from phiB (bf16), 16 batch rows per block, thread = (row, class)
__global__ __launch_bounds__(256) void logits_kernel(
    const u16* __restrict__ phiB, const float* __restrict__ bw,
    const float* __restrict__ bbias, float* __restrict__ out,
    float* __restrict__ wmat)
{
  __shared__ float ph[16][132];
  __shared__ float bwl[16][132];
  __shared__ float lg[16][17];
  const int b0 = blockIdx.x * 16;
  const int tid = threadIdx.x;
  const int bl = tid & 15, kq = tid >> 4;
  float acc = 0.f;
  for (int kb = 0; kb < NIND; kb += 128) {
    {
      int row = tid >> 4, c8 = (tid & 15) << 3;
      uint4 v = *(const uint4*)(phiB + (size_t)(b0 + row) * NIND + kb + c8);
      const unsigned* u = (const unsigned*)&v;
      #pragma unroll
      for (int j = 0; j < 4; ++j) {
        ph[row][c8 + 2*j]     = bflo(u[j]);
        ph[row][c8 + 2*j + 1] = bfhi(u[j]);
      }
    }
    #pragma unroll
    for (int t = 0; t < 2; ++t) {
      int f = t * 256 + tid;
      int row = f >> 5, c4 = (f & 31) << 2;
      *(float4*)(&bwl[row][c4]) = *(const float4*)(bw + (size_t)row * NIND + kb + c4);
    }
    __syncthreads();
    #pragma unroll 8
    for (int q = 0; q < 128; q += 4) {
      float4 a = *(const float4*)(&ph[bl][q]);
      float4 b4 = *(const float4*)(&bwl[kq][q]);
      acc += a.x*b4.x + a.y*b4.y + a.z*b4.z + a.w*b4.w;
    }
    __syncthreads();
  }
  float v = acc + bbias[kq];
  lg[bl][kq] = v;
  out[(size_t)(b0 + bl) * NCLS + kq] = v;
  __syncthreads();
  if (tid < 16) {
    float mx = -1e30f;
    #pragma unroll
    for (int k = 0; k < 16; ++k) mx = fmaxf(mx, lg[tid][k]);
    float s = 0.f, ex[16];
    #pragma unroll
    for (int k = 0; k < 16; ++k) { ex[k] = expf(lg[tid][k] - mx); s += ex[k]; }
    float inv = 1.0f / s;
    #pragma unroll
    for (int k = 0; k < 16; ++k) {
      float p = ex[k] * inv;
      wmat[(size_t)k * BATCH + b0 + tid] = p * (1.0f - p);
    }
  }
}

// K2b: phiW[k][i][b] = bf16(wmat[k][b] * phi[i][b])  (from bf16 phiTB)
__global__ __launch_bounds__(256) void scalew_kernel(
    const u16* __restrict__ phiTB, const float* __restrict__ wmat,
    u16* __restrict__ phiW)
{
  const int k = blockIdx.y;
  size_t flat = ((size_t)blockIdx.x * 256 + threadIdx.x) * 8;
  int b = (int)(flat & 2047);
  uint4 pv = *(const uint4*)(phiTB + flat);
  float4 w0 = *(const float4*)(wmat + (size_t)k * BATCH + b);
  float4 w1 = *(const float4*)(wmat + (size_t)k * BATCH + b + 4);
  float wv[8] = {w0.x, w0.y, w0.z, w0.w, w1.x, w1.y, w1.z, w1.w};
  *(uint4*)(phiW + (size_t)k * NIND * BATCH + flat) = scale8(pv, wv);
}

// K3: MFMA bf16 gram -> Pb bf16. FULL 64-tile grid (4 blocks/CU hides the
// 2-barrier-per-K-step latency; R17-verified). XCD = ti.
__global__ __launch_bounds__(256) void gram_kernel(
    const u16* __restrict__ phiW, const u16* __restrict__ phiTB,
    const float* __restrict__ prec, u16* __restrict__ Pb)
{
  __shared__ u16 Als[128 * 64];
  __shared__ u16 Bls[128 * 64];
  const int ti = blockIdx.x & 7, tj = blockIdx.x >> 3;   // XCD = ti
  const int k = blockIdx.y;
  const int i0 = ti * 128, j0 = tj * 128;
  const int tid = threadIdx.x;
  const int wid = tid >> 6, lane = tid & 63;
  const int wr = wid >> 1, wc = wid & 1;
  const u16* Ag = phiW + (size_t)k * NIND * BATCH + (size_t)i0 * BATCH;
  const u16* Bg = phiTB + (size_t)j0 * BATCH;
  f32x4 acc[4][4];
  #pragma unroll
  for (int m = 0; m < 4; ++m)
    #pragma unroll
    for (int n = 0; n < 4; ++n) acc[m][n] = (f32x4){0.f, 0.f, 0.f, 0.f};
  for (int b0 = 0; b0 < BATCH; b0 += 64) {
    #pragma unroll
    for (int c = 0; c < 4; ++c) {
      int f = c * 256 + tid;
      int row = f >> 3, s = f & 7;
      int sc = (s ^ (row & 7)) << 3;
      gload16(Ag + (size_t)row * BATCH + b0 + sc, Als + ((c * 256 + wid * 64) << 3));
      gload16(Bg + (size_t)row * BATCH + b0 + sc, Bls + ((c * 256 + wid * 64) << 3));
    }
    __syncthreads();
    #pragma unroll
    for (int ks = 0; ks < 2; ++ks) {
      bf16x8 af[4], bfr[4];
      #pragma unroll
      for (int m = 0; m < 4; ++m) {
        int row = wr * 64 + m * 16 + (lane & 15);
        int kb = ks * 32 + (lane >> 4) * 8;
        int idx = (row * 64 + kb) ^ ((row & 7) << 3);
        af[m] = *(const bf16x8*)(&Als[idx]);
      }
      #pragma unroll
      for (int n = 0; n < 4; ++n) {
        int row = wc * 64 + n * 16 + (lane & 15);
        int kb = ks * 32 + (lane >> 4) * 8;
        int idx = (row * 64 + kb) ^ ((row & 7) << 3);
        bfr[n] = *(const bf16x8*)(&Bls[idx]);
      }
      #pragma unroll
      for (int m = 0; m < 4; ++m)
        #pragma unroll
        for (int n = 0; n < 4; ++n)
          acc[m][n] = __builtin_amdgcn_mfma_f32_16x16x32_bf16(af[m], bfr[n], acc[m][n], 0, 0, 0);
    }
    __syncthreads();
  }
  const size_t kb2 = (size_t)k * NIND * NIND;
  #pragma unroll
  for (int m = 0; m < 4; ++m) {
    #pragma unroll
    for (int n = 0; n < 4; ++n) {
      #pragma unroll
      for (int r = 0; r < 4; ++r) {
        int gi = i0 + wr * 64 + m * 16 + (lane >> 4) * 4 + r;
        int gj = j0 + wc * 64 + n * 16 + (lane & 15);
        size_t idx = kb2 + (size_t)gi * NIND + gj;
        float v = acc[m][n][r] + prec[idx];
        Pb[idx] = (u16)f2bf(v);
      }
    }
  }
}

// K4: Gershgorin bound per class: gmax[k] = max_i sum_j |P_ij| (certified >= lambda_max)
__global__ __launch_bounds__(256) void gersh_kernel(
    const u16* __restrict__ Pb, unsigned* __restrict__ gmax)
{
  __shared__ float psum[64][17];
  const int k = blockIdx.y, rbk = blockIdx.x;
  const int tid = threadIdx.x;
  const size_t mb = (size_t)k * NIND * NIND;
  #pragma unroll
  for (int p = 0; p < 4; ++p) {
    int rl = p * 16 + (tid >> 4);
    int row = rbk * 64 + rl;
    int ch = tid & 15;
    float s = 0.f;
    const u16* base = Pb + mb + (size_t)row * NIND + ch * 64;
    #pragma unroll
    for (int c8 = 0; c8 < 8; ++c8) {
      uint4 u = *(const uint4*)(base + c8 * 8);
      const unsigned* uu = (const unsigned*)&u;
      #pragma unroll
      for (int q = 0; q < 4; ++q)
        s += fabsf(bflo(uu[q])) + fabsf(bfhi(uu[q]));
    }
    psum[rl][ch] = s;
  }
  __syncthreads();
  if (tid < 64) {
    float s = 0.f;
    #pragma unroll
    for (int j = 0; j < 16; ++j) s += psum[tid][j];
    psum[tid][16] = s;
  }
  __syncthreads();
  if (tid == 0) {
    float mx = 0.f;
    for (int t = 0; t < 64; ++t) mx = fmaxf(mx, psum[t][16]);
    atomicMax(gmax + k, __float_as_uint(mx));
  }
}

// K6: GEMM C = A (*) B^T with epilogue modes. Full 64 tiles, XCD swizzle.
// mode 0: C = acc
// mode 1: C = 2*Xadd - acc                      (Newton second half)
// mode 2: C = a3*acc + a2*Xadd + a1*Pex + a0*I  (deg-3 Chebyshev init, R13-validated)
// mode 3: mode 1, then double entries whose 128-tiles differ (pre-weights M for
//         the triangular-K quadratic form in vgemm; phi^T M phi only sees sym(M))
__global__ __launch_bounds__(256) void ntgemm_kernel(
    const u16* __restrict__ A, const u16* __restrict__ B,
    const u16* __restrict__ Xadd, const u16* __restrict__ Pex,
    const unsigned* __restrict__ gmax, u16* __restrict__ C, int mode)
{
  __shared__ u16 Als[128 * 64];
  __shared__ u16 Bls[128 * 64];
  const int k = blockIdx.y;
  const int ti = blockIdx.x & 7, tj = blockIdx.x >> 3;   // XCD swizzle (T1)
  const int i0 = ti * 128, j0 = tj * 128;
  const int tid = threadIdx.x;
  const int wid = tid >> 6, lane = tid & 63;
  const int wr = wid >> 1, wc = wid & 1;
  const size_t mb = (size_t)k * NIND * NIND;
  const u16* Ag = A + mb + (size_t)i0 * NIND;
  const u16* Bg = B + mb + (size_t)j0 * NIND;
  f32x4 acc[4][4];
  #pragma unroll
  for (int m = 0; m < 4; ++m)
    #pragma unroll
    for (int n = 0; n < 4; ++n) acc[m][n] = (f32x4){0.f, 0.f, 0.f, 0.f};
  for (int kb = 0; kb < NIND; kb += 64) {
    #pragma unroll
    for (int c = 0; c < 4; ++c) {
      int f = c * 256 + tid;
      int row = f >> 3, s = f & 7;
      int sc = (s ^ (row & 7)) << 3;
      gload16(Ag + (size_t)row * NIND + kb + sc, Als + ((c * 256 + wid * 64) << 3));
      gload16(Bg + (size_t)row * NIND + kb + sc, Bls + ((c * 256 + wid * 64) << 3));
    }
    __syncthreads();
    #pragma unroll
    for (int ks = 0; ks < 2; ++ks) {
      bf16x8 af[4], bfr[4];
      #pragma unroll
      for (int m = 0; m < 4; ++m) {
        int row = wr * 64 + m * 16 + (lane & 15);
        int kq = ks * 32 + (lane >> 4) * 8;
        int idx = (row * 64 + kq) ^ ((row & 7) << 3);
        af[m] = *(const bf16x8*)(&Als[idx]);
      }
      #pragma unroll
      for (int n = 0; n < 4; ++n) {
        int row = wc * 64 + n * 16 + (lane & 15);
        int kq = ks * 32 + (lane >> 4) * 8;
        int idx = (row * 64 + kq) ^ ((row & 7) << 3);
        bfr[n] = *(const bf16x8*)(&Bls[idx]);
      }
      #pragma unroll
      for (int m = 0; m < 4; ++m)
        #pragma unroll
        for (int n = 0; n < 4; ++n)
          acc[m][n] = __builtin_amdgcn_mfma_f32_16x16x32_bf16(af[m], bfr[n], acc[m][n], 0, 0, 0);
    }
    __syncthreads();
  }
  float a0 = 0.f, a1 = 0.f, a2 = 0.f, a3 = 0.f;
  if (mode == 2) {
    float G = __uint_as_float(gmax[k]) * 1.001f + 0.01f;
    if (G < 1.05f) G = 1.05f;
    float s = 1.0f + G, dd = G - 1.0f;
    float s2 = s * s, d2 = dd * dd;
    float D = 8.0f * s2 * s2 - 8.0f * d2 * s2 + d2 * d2;
    a3 = -128.0f / D;
    a2 = 256.0f * s / D;
    a1 = -(192.0f * s2 - 32.0f * d2) / D;
    a0 = (64.0f * s2 * s - 32.0f * d2 * s) / D;
  }
  #pragma unroll
  for (int m = 0; m < 4; ++m) {
    #pragma unroll
    for (int n = 0; n < 4; ++n) {
      #pragma unroll
      for (int r = 0; r < 4; ++r) {
        int gi = i0 + wr * 64 + m * 16 + (lane >> 4) * 4 + r;
        int gj = j0 + wc * 64 + n * 16 + (lane & 15);
        size_t idx = mb + (size_t)gi * NIND + gj;
        float v = acc[m][n][r];
        if (mode == 1 || mode == 3) {
          v = 2.0f * bflo((unsigned)Xadd[idx]) - v;
          if (mode == 3 && ti != tj) v *= 2.0f;
        } else if (mode == 2) {
          v = a3 * v + a2 * bflo((unsigned)Xadd[idx]) + a1 * bflo((unsigned)Pex[idx]);
          if (gi == gj) v += a0;
        }
        C[idx] = (u16)f2bf(v);
      }
    }
  }
}

// K7 v2: balanced triangular variance GEMM. Block = (btile, pr); sequentially
// computes TWO row-blocks It0=pr and It1=7-pr, each with triangular K from
// It*128: (8-pr) + (1+pr) = 9 K-tiles per block, uniform. M tile-off-diag
// pre-doubled (mode 3) so triangular K gives phi^T sym(M) phi exactly.
__global__ __launch_bounds__(256) void vgemm_kernel(
    const u16* __restrict__ phiB, const u16* __restrict__ M,
    float* __restrict__ partial)
{
  __shared__ u16 Als[128 * 64];
  __shared__ u16 Bls[128 * 64];
  __shared__ float red[128][33];
  const int btile = blockIdx.x >> 2, pr = blockIdx.x & 3;
  const int k = blockIdx.y;
  const int b0 = btile * 128;
  const int tid = threadIdx.x;
  const int wid = tid >> 6, lane = tid & 63;
  const int wr = wid >> 1, wc = wid & 1;
  const int q = lane >> 4, l15 = lane & 15;
  const u16* Ag = phiB + (size_t)b0 * NIND;
  #pragma unroll
  for (int ph = 0; ph < 2; ++ph) {
    const int It = ph ? (7 - pr) : pr;
    const int i0 = It * 128;
    const u16* Bg = M + (size_t)k * NIND * NIND + (size_t)i0 * NIND;
    f32x4 acc[4][4];
    #pragma unroll
    for (int m = 0; m < 4; ++m)
      #pragma unroll
      for (int n = 0; n < 4; ++n) acc[m][n] = (f32x4){0.f, 0.f, 0.f, 0.f};
    for (int kb = i0; kb < NIND; kb += 64) {
      #pragma unroll
      for (int c = 0; c < 4; ++c) {
        int f = c * 256 + tid;
        int row = f >> 3, s = f & 7;
        int sc = (s ^ (row & 7)) << 3;
        gload16(Ag + (size_t)row * NIND + kb + sc, Als + ((c * 256 + wid * 64) << 3));
        gload16(Bg + (size_t)row * NIND + kb + sc, Bls + ((c * 256 + wid * 64) << 3));
      }
      __syncthreads();
      #pragma unroll
      for (int ks = 0; ks < 2; ++ks) {
        bf16x8 af[4], bfr[4];
        #pragma unroll
        for (int m = 0; m < 4; ++m) {
          int row = wr * 64 + m * 16 + l15;
          int kq = ks * 32 + q * 8;
          int idx = (row * 64 + kq) ^ ((row & 7) << 3);
          af[m] = *(const bf16x8*)(&Als[idx]);
        }
        #pragma unroll
        for (int n = 0; n < 4; ++n) {
          int row = wc * 64 + n * 16 + l15;
          int kq = ks * 32 + q * 8;
          int idx = (row * 64 + kq) ^ ((row & 7) << 3);
          bfr[n] = *(const bf16x8*)(&Bls[idx]);
        }
        #pragma unroll
        for (int m = 0; m < 4; ++m)
          #pragma unroll
          for (int n = 0; n < 4; ++n)
            acc[m][n] = __builtin_amdgcn_mfma_f32_16x16x32_bf16(af[m], bfr[n], acc[m][n], 0, 0, 0);
      }
      __syncthreads();
    }
    float vs[4][4] = {};
    #pragma unroll
    for (int m = 0; m < 4; ++m) {
      #pragma unroll
      for (int r = 0; r < 4; ++r) {
        int gb = b0 + wr * 64 + m * 16 + q * 4 + r;
        #pragma unroll
        for (int n = 0; n < 4; ++n) {
          int gi = i0 + wc * 64 + n * 16 + l15;
          float pv = bflo((unsigned)phiB[(size_t)gb * NIND + gi]);
          vs[m][r] += acc[m][n][r] * pv;
        }
      }
    }
    #pragma unroll
    for (int m = 0; m < 4; ++m)
      #pragma unroll
      for (int r = 0; r < 4; ++r)
        red[wr * 64 + m * 16 + q * 4 + r][wc * 16 + l15] = vs[m][r];
    __syncthreads();
    if (tid < 128) {
      float s = 0.f;
      #pragma unroll
      for (int t = 0; t < 32; ++t) s += red[tid][t];
      partial[((size_t)It * NCLS + k) * BATCH + b0 + tid] = s;
    }
    __syncthreads();
  }
}

// K8: out variances[b][k] = sum_It partial[It][k][b]
__global__ __launch_bounds__(256) void reduce_kernel(
    const float* __restrict__ partial, float* __restrict__ out)
{
  int t = blockIdx.x * 256 + threadIdx.x;
  int k = t >> 11, b = t & 2047;
  float s = 0.f;
  #pragma unroll
  for (int It = 0; It < 8; ++It)
    s += partial[((size_t)It * NCLS + k) * BATCH + b];
  out[(size_t)BATCH * NCLS + (size_t)b * NCLS + k] = s;
}

extern "C" void kernel_launch(void* const* d_in, const int* in_sizes, int n_in,
                              void* d_out, int out_size, void* d_ws, size_t ws_size,
                              hipStream_t stream)
{
  (void)in_sizes; (void)n_in; (void)ws_size; (void)out_size;
  const float* x   = (const float*)d_in[0];
  const float* rw  = (const float*)d_in[1];
  const float* rb  = (const float*)d_in[2];
  const float* bw  = (const float*)d_in[3];
  const float* bb  = (const float*)d_in[4];
  const float* prc = (const float*)d_in[5];
  float* out = (float*)d_out;
  char* ws = (char*)d_ws;
  size_t off = 0;
  auto alloc = [&](size_t bytes) -> void* {
    void* p = ws + off;
    off = (off + bytes + 255) & ~(size_t)255;
    return p;
  };
  const size_t MSZ = (size_t)NCLS * NIND * NIND * 2;   // 32MB bf16 matrix
  u16*   xB     = (u16*)  alloc((size_t)BATCH * FEAT * 2);
  u16*   rwT    = (u16*)  alloc((size_t)NIND * FEAT * 2);
  u16*   phiB   = (u16*)  alloc((size_t)BATCH * NIND * 2);
  u16*   phiTB  = (u16*)  alloc((size_t)NIND * BATCH * 2);
  float* wmat   = (float*)alloc((size_t)NCLS * BATCH * 4);
  u16*   Pb     = (u16*)  alloc(MSZ);
  unsigned* gbound = (unsigned*)alloc((size_t)NCLS * 4);
  float* partial = (float*)alloc((size_t)8 * NCLS * BATCH * 4);
  u16*   Xa     = (u16*)alloc(MSZ);
  u16*   B2     = (u16*)alloc(MSZ);
  u16*   BY     = (u16*)alloc(MSZ);
  // phiW (64MB) aliases Xa+B2 (contiguous): dead before G2 writes Xa.
  u16*   phiW   = Xa;

  hipMemsetAsync(gbound, 0, (size_t)NCLS * 4, stream);
  xcast_kernel<<<dim3(BATCH * FEAT / 2048), 256, 0, stream>>>(x, xB);
  rwt_kernel<<<dim3(FEAT / 64, NIND / 64), 256, 0, stream>>>(rw, rwT);
  phimm_kernel<<<dim3(BATCH / 128, NIND / 128), 256, 0, stream>>>(xB, rwT, rb, phiB, phiTB);
  logits_kernel<<<dim3(BATCH / 16), 256, 0, stream>>>(phiB, bw, bb, out, wmat);
  scalew_kernel<<<dim3(1024, NCLS), 256, 0, stream>>>(phiTB, wmat, phiW);
  gram_kernel<<<dim3(64, NCLS), 256, 0, stream>>>(phiW, phiTB, prc, Pb);
  gersh_kernel<<<dim3(16, NCLS), 256, 0, stream>>>(Pb, gbound);
  const dim3 gg(64, NCLS);
  // G1: BY = P^2
  ntgemm_kernel<<<gg, 256, 0, stream>>>(Pb, Pb, (u16*)nullptr, (u16*)nullptr,
                                        (unsigned*)nullptr, BY, 0);
  // G2: Xa = a3*P^3 + a2*P^2 + a1*P + a0*I  (cheb-3 fused into the P^3 GEMM)
  ntgemm_kernel<<<gg, 256, 0, stream>>>(BY, Pb, BY, Pb, gbound, Xa, 2);
  // G3+G4: one Newton iteration: BY = Xa*P ; B2 = (2*Xa - Xa*BY^T) with
  // tile-off-diagonal entries doubled (mode 3) for the triangular vgemm.
  ntgemm_kernel<<<gg, 256, 0, stream>>>(Xa, Pb, (u16*)nullptr, (u16*)nullptr,
                                        (unsigned*)nullptr, BY, 0);
  ntgemm_kernel<<<gg, 256, 0, stream>>>(Xa, BY, Xa, (u16*)nullptr,
                                        (unsigned*)nullptr, B2, 3);
  // variances: var_b = phi^T sym(M) phi via balanced triangular K (9 tiles/block)
  vgemm_kernel<<<dim3(64, NCLS), 256, 0, stream>>>(phiB, B2, partial);
  reduce_kernel<<<dim3(128), 256, 0, stream>>>(partial, out);
}

// Round 21
// 508.977 us; speedup vs baseline: 1.0686x; 1.0186x over previous
//
#include <hip/hip_runtime.h>
#include <hip/hip_bf16.h>

#define BATCH 2048
#define FEAT  768
#define NIND  1024
#define NCLS  16

typedef unsigned short u16;
typedef __attribute__((ext_vector_type(8))) __bf16 bf16x8;
typedef __attribute__((ext_vector_type(4))) float f32x4;

static __device__ __forceinline__ unsigned f2bf(float f) {
  unsigned u = __float_as_uint(f);
  unsigned r = ((u >> 16) & 1u) + 0x7FFFu;
  return (u + r) >> 16;                       // RNE bf16 in low 16 bits
}
static __device__ __forceinline__ float bflo(unsigned x) {
  return __uint_as_float((x & 0xFFFFu) << 16);
}
static __device__ __forceinline__ float bfhi(unsigned x) {
  return __uint_as_float(x & 0xFFFF0000u);
}

// async 16B global->LDS (LDS dest = wave-uniform base + lane*16)
static __device__ __forceinline__ void gload16(const u16* g, u16* l) {
  __builtin_amdgcn_global_load_lds(
      (const __attribute__((address_space(1))) void*)g,
      (__attribute__((address_space(3))) void*)l, 16, 0, 0);
}

// pack 8 bf16 (as uint4) scaled by wv[0..7] back to 8 bf16 (uint4)
static __device__ __forceinline__ uint4 scale8(uint4 v, const float* wv) {
  unsigned out[4];
  const unsigned* in = (const unsigned*)&v;
  #pragma unroll
  for (int i = 0; i < 4; ++i) {
    float lo = bflo(in[i]) * wv[2*i];
    float hi = bfhi(in[i]) * wv[2*i+1];
    __hip_bfloat162 pk = __float22bfloat162_rn(float2{lo, hi});
    out[i] = *(unsigned*)&pk;
  }
  return uint4{out[0], out[1], out[2], out[3]};
}

// K0a: xB = bf16(x), elementwise
__global__ __launch_bounds__(256) void xcast_kernel(
    const float* __restrict__ x, u16* __restrict__ xB)
{
  size_t f = ((size_t)blockIdx.x * 256 + threadIdx.x) * 8;
  float4 a = *(const float4*)(x + f);
  float4 b = *(const float4*)(x + f + 4);
  uint4 o;
  o.x = (f2bf(a.x) & 0xFFFFu) | (f2bf(a.y) << 16);
  o.y = (f2bf(a.z) & 0xFFFFu) | (f2bf(a.w) << 16);
  o.z = (f2bf(b.x) & 0xFFFFu) | (f2bf(b.y) << 16);
  o.w = (f2bf(b.z) & 0xFFFFu) | (f2bf(b.w) << 16);
  *(uint4*)(xB + f) = o;
}

// K0b: rwT[i][k] = bf16(rw[k][i])  (LDS-tiled transpose)
__global__ __launch_bounds__(256) void rwt_kernel(
    const float* __restrict__ rw, u16* __restrict__ rwT)
{
  __shared__ float ts[64][65];
  const int k0 = blockIdx.x * 64, i0 = blockIdx.y * 64;
  const int tid = threadIdx.x;
  #pragma unroll
  for (int t = 0; t < 4; ++t) {
    int f = t * 256 + tid;
    int r = f >> 4, c4 = (f & 15) << 2;
    *(float4*)(&ts[r][c4]) = *(const float4*)(rw + (size_t)(k0 + r) * NIND + i0 + c4);
  }
  __syncthreads();
  #pragma unroll
  for (int t = 0; t < 4; ++t) {
    int f = t * 256 + tid;
    int r = f >> 4, c4 = (f & 15) << 2;   // r = i-local, c4 = k-local base
    uint2 o;
    o.x = (f2bf(ts[c4+0][r]) & 0xFFFFu) | (f2bf(ts[c4+1][r]) << 16);
    o.y = (f2bf(ts[c4+2][r]) & 0xFFFFu) | (f2bf(ts[c4+3][r]) << 16);
    *(uint2*)(rwT + (size_t)(i0 + r) * FEAT + k0 + c4) = o;
  }
}

// K1: MFMA phi. phiB[b][i], phiTB[i][b] = bf16(SC*cos(2*(x@W+b))). K=768.
__global__ __launch_bounds__(256) void phimm_kernel(
    const u16* __restrict__ xB, const u16* __restrict__ rwT,
    const float* __restrict__ rb, u16* __restrict__ phiB,
    u16* __restrict__ phiTB)
{
  __shared__ u16 sh[128 * 128];      // staging (2x 128x64) then transpose tile
  u16* Als = sh;
  u16* Bls = sh + 8192;
  const int b0 = blockIdx.x * 128, i0 = blockIdx.y * 128;
  const int tid = threadIdx.x;
  const int wid = tid >> 6, lane = tid & 63;
  const int wr = wid >> 1, wc = wid & 1;
  const u16* Ag = xB + (size_t)b0 * FEAT;
  const u16* Bg = rwT + (size_t)i0 * FEAT;
  f32x4 acc[4][4];
  #pragma unroll
  for (int m = 0; m < 4; ++m)
    #pragma unroll
    for (int n = 0; n < 4; ++n) acc[m][n] = (f32x4){0.f, 0.f, 0.f, 0.f};
  for (int kb = 0; kb < FEAT; kb += 64) {
    #pragma unroll
    for (int c = 0; c < 4; ++c) {
      int f = c * 256 + tid;
      int row = f >> 3, s = f & 7;
      int sc = (s ^ (row & 7)) << 3;
      gload16(Ag + (size_t)row * FEAT + kb + sc, Als + ((c * 256 + wid * 64) << 3));
      gload16(Bg + (size_t)row * FEAT + kb + sc, Bls + ((c * 256 + wid * 64) << 3));
    }
    __syncthreads();
    #pragma unroll
    for (int ks = 0; ks < 2; ++ks) {
      bf16x8 af[4], bfr[4];
      #pragma unroll
      for (int m = 0; m < 4; ++m) {
        int row = wr * 64 + m * 16 + (lane & 15);
        int kq = ks * 32 + (lane >> 4) * 8;
        int idx = (row * 64 + kq) ^ ((row & 7) << 3);
        af[m] = *(const bf16x8*)(&Als[idx]);
      }
      #pragma unroll
      for (int n = 0; n < 4; ++n) {
        int row = wc * 64 + n * 16 + (lane & 15);
        int kq = ks * 32 + (lane >> 4) * 8;
        int idx = (row * 64 + kq) ^ ((row & 7) << 3);
        bfr[n] = *(const bf16x8*)(&Bls[idx]);
      }
      #pragma unroll
      for (int m = 0; m < 4; ++m)
        #pragma unroll
        for (int n = 0; n < 4; ++n)
          acc[m][n] = __builtin_amdgcn_mfma_f32_16x16x32_bf16(af[m], bfr[n], acc[m][n], 0, 0, 0);
    }
    __syncthreads();
  }
  const float SC = 0.04419417382415922f;   // sqrt(2/1024)
  float rbl[4];
  #pragma unroll
  for (int n = 0; n < 4; ++n) rbl[n] = rb[i0 + wc * 64 + n * 16 + (lane & 15)];
  #pragma unroll
  for (int m = 0; m < 4; ++m) {
    #pragma unroll
    for (int n = 0; n < 4; ++n) {
      #pragma unroll
      for (int r = 0; r < 4; ++r) {
        int lb = wr * 64 + m * 16 + (lane >> 4) * 4 + r;
        int li = wc * 64 + n * 16 + (lane & 15);
        float proj = 2.0f * (acc[m][n][r] + rbl[n]);
        u16 bv = (u16)f2bf(SC * cosf(proj));
        phiB[(size_t)(b0 + lb) * NIND + i0 + li] = bv;
        int idx = (li * 128 + lb) ^ ((li & 7) << 3);
        sh[idx] = bv;
      }
    }
  }
  __syncthreads();
  #pragma unroll
  for (int t = 0; t < 8; ++t) {
    int f = t * 256 + tid;             // 2048 uint4-slots over 128x128 u16
    int li = f >> 4, c8 = (f & 15) << 3;
    int idx = (li * 128 + c8) ^ ((li & 7) << 3);
    uint4 v = *(const uint4*)(&sh[idx]);
    *(uint4*)(phiTB + (size_t)(i0 + li) * BATCH + b0 + c8) = v;
  }
}

// K2: logits from phiB (bf16), 16 batch rows per block, thread = (row, class)
__global__ __launch_bounds__(256) void logits_kernel(
    const u16* __restrict__ phiB, const float* __restrict__ bw,
    const float* __restrict__ bbias, float* __restrict__ out,
    float* __restrict__ wmat)
{
  __shared__ float ph[16][132];
  __shared__ float bwl[16][132];
  __shared__ float lg[16][17];
  const int b0 = blockIdx.x * 16;
  const int tid = threadIdx.x;
  const int bl = tid & 15, kq = tid >> 4;
  float acc = 0.f;
  for (int kb = 0; kb < NIND; kb += 128) {
    {
      int row = tid >> 4, c8 = (tid & 15) << 3;
      uint4 v = *(const uint4*)(phiB + (size_t)(b0 + row) * NIND + kb + c8);
      const unsigned* u = (const unsigned*)&v;
      #pragma unroll
      for (int j = 0; j < 4; ++j) {
        ph[row][c8 + 2*j]     = bflo(u[j]);
        ph[row][c8 + 2*j + 1] = bfhi(u[j]);
      }
    }
    #pragma unroll
    for (int t = 0; t < 2; ++t) {
      int f = t * 256 + tid;
      int row = f >> 5, c4 = (f & 31) << 2;
      *(float4*)(&bwl[row][c4]) = *(const float4*)(bw + (size_t)row * NIND + kb + c4);
    }
    __syncthreads();
    #pragma unroll 8
    for (int q = 0; q < 128; q += 4) {
      float4 a = *(const float4*)(&ph[bl][q]);
      float4 b4 = *(const float4*)(&bwl[kq][q]);
      acc += a.x*b4.x + a.y*b4.y + a.z*b4.z + a.w*b4.w;
    }
    __syncthreads();
  }
  float v = acc + bbias[kq];
  lg[bl][kq] = v;
  out[(size_t)(b0 + bl) * NCLS + kq] = v;
  __syncthreads();
  if (tid < 16) {
    float mx = -1e30f;
    #pragma unroll
    for (int k = 0; k < 16; ++k) mx = fmaxf(mx, lg[tid][k]);
    float s = 0.f, ex[16];
    #pragma unroll
    for (int k = 0; k < 16; ++k) { ex[k] = expf(lg[tid][k] - mx); s += ex[k]; }
    float inv = 1.0f / s;
    #pragma unroll
    for (int k = 0; k < 16; ++k) {
      float p = ex[k] * inv;
      wmat[(size_t)k * BATCH + b0 + tid] = p * (1.0f - p);
    }
  }
}

// K2b: phiW[k][i][b] = bf16(wmat[k][b] * phi[i][b])  (from bf16 phiTB)
__global__ __launch_bounds__(256) void scalew_kernel(
    const u16* __restrict__ phiTB, const float* __restrict__ wmat,
    u16* __restrict__ phiW)
{
  const int k = blockIdx.y;
  size_t flat = ((size_t)blockIdx.x * 256 + threadIdx.x) * 8;
  int b = (int)(flat & 2047);
  uint4 pv = *(const uint4*)(phiTB + flat);
  float4 w0 = *(const float4*)(wmat + (size_t)k * BATCH + b);
  float4 w1 = *(const float4*)(wmat + (size_t)k * BATCH + b + 4);
  float wv[8] = {w0.x, w0.y, w0.z, w0.w, w1.x, w1.y, w1.z, w1.w};
  *(uint4*)(phiW + (size_t)k * NIND * BATCH + flat) = scale8(pv, wv);
}

// K3: MFMA bf16 gram -> Pb bf16. FULL 64-tile grid (4 blocks/CU; R17-verified).
// XCD = ti. Epilogue also emits per-row |P| partials (Gershgorin fold): each
// (k, tj, wc) slice has a unique writer per row -> deterministic, no atomics.
__global__ __launch_bounds__(256) void gram_kernel(
    const u16* __restrict__ phiW, const u16* __restrict__ phiTB,
    const float* __restrict__ prec, u16* __restrict__ Pb,
    float* __restrict__ rowAbs)
{
  __shared__ u16 Als[128 * 64];
  __shared__ u16 Bls[128 * 64];
  const int ti = blockIdx.x & 7, tj = blockIdx.x >> 3;   // XCD = ti
  const int k = blockIdx.y;
  const int i0 = ti * 128, j0 = tj * 128;
  const int tid = threadIdx.x;
  const int wid = tid >> 6, lane = tid & 63;
  const int wr = wid >> 1, wc = wid & 1;
  const u16* Ag = phiW + (size_t)k * NIND * BATCH + (size_t)i0 * BATCH;
  const u16* Bg = phiTB + (size_t)j0 * BATCH;
  f32x4 acc[4][4];
  #pragma unroll
  for (int m = 0; m < 4; ++m)
    #pragma unroll
    for (int n = 0; n < 4; ++n) acc[m][n] = (f32x4){0.f, 0.f, 0.f, 0.f};
  for (int b0 = 0; b0 < BATCH; b0 += 64) {
    #pragma unroll
    for (int c = 0; c < 4; ++c) {
      int f = c * 256 + tid;
      int row = f >> 3, s = f & 7;
      int sc = (s ^ (row & 7)) << 3;
      gload16(Ag + (size_t)row * BATCH + b0 + sc, Als + ((c * 256 + wid * 64) << 3));
      gload16(Bg + (size_t)row * BATCH + b0 + sc, Bls + ((c * 256 + wid * 64) << 3));
    }
    __syncthreads();
    #pragma unroll
    for (int ks = 0; ks < 2; ++ks) {
      bf16x8 af[4], bfr[4];
      #pragma unroll
      for (int m = 0; m < 4; ++m) {
        int row = wr * 64 + m * 16 + (lane & 15);
        int kb = ks * 32 + (lane >> 4) * 8;
        int idx = (row * 64 + kb) ^ ((row & 7) << 3);
        af[m] = *(const bf16x8*)(&Als[idx]);
      }
      #pragma unroll
      for (int n = 0; n < 4; ++n) {
        int row = wc * 64 + n * 16 + (lane & 15);
        int kb = ks * 32 + (lane >> 4) * 8;
        int idx = (row * 64 + kb) ^ ((row & 7) << 3);
        bfr[n] = *(const bf16x8*)(&Bls[idx]);
      }
      #pragma unroll
      for (int m = 0; m < 4; ++m)
        #pragma unroll
        for (int n = 0; n < 4; ++n)
          acc[m][n] = __builtin_amdgcn_mfma_f32_16x16x32_bf16(af[m], bfr[n], acc[m][n], 0, 0, 0);
    }
    __syncthreads();
  }
  const size_t kb2 = (size_t)k * NIND * NIND;
  float sabs[4][4];
  #pragma unroll
  for (int m = 0; m < 4; ++m)
    #pragma unroll
    for (int r = 0; r < 4; ++r) sabs[m][r] = 0.f;
  #pragma unroll
  for (int m = 0; m < 4; ++m) {
    #pragma unroll
    for (int n = 0; n < 4; ++n) {
      #pragma unroll
      for (int r = 0; r < 4; ++r) {
        int gi = i0 + wr * 64 + m * 16 + (lane >> 4) * 4 + r;
        int gj = j0 + wc * 64 + n * 16 + (lane & 15);
        size_t idx = kb2 + (size_t)gi * NIND + gj;
        float v = acc[m][n][r] + prec[idx];
        u16 bv = (u16)f2bf(v);
        Pb[idx] = bv;
        sabs[m][r] += fabsf(__uint_as_float((unsigned)bv << 16));
      }
    }
  }
  // butterfly over the 16 column-lanes (gi depends only on lane>>4) -> row sums
  float* rp = rowAbs + ((size_t)k * 16 + tj * 2 + wc) * NIND + i0;
  #pragma unroll
  for (int m = 0; m < 4; ++m) {
    #pragma unroll
    for (int r = 0; r < 4; ++r) {
      float s = sabs[m][r];
      s += __shfl_xor(s, 1);
      s += __shfl_xor(s, 2);
      s += __shfl_xor(s, 4);
      s += __shfl_xor(s, 8);
      if ((lane & 15) == 0)
        rp[wr * 64 + m * 16 + (lane >> 4) * 4 + r] = s;
    }
  }
}

// K4: gersh2 -- G[k] = max_row sum over the 16 rowAbs slices (1MB total read)
__global__ __launch_bounds__(256) void gersh2_kernel(
    const float* __restrict__ rowAbs, unsigned* __restrict__ gmax)
{
  __shared__ float red[256];
  const int k = blockIdx.x, tid = threadIdx.x;
  const float* base = rowAbs + (size_t)k * 16 * NIND;
  float mx = 0.f;
  for (int row = tid; row < NIND; row += 256) {
    float s = 0.f;
    #pragma unroll
    for (int sl = 0; sl < 16; ++sl) s += base[(size_t)sl * NIND + row];
    mx = fmaxf(mx, s);
  }
  red[tid] = mx;
  __syncthreads();
  for (int o = 128; o > 0; o >>= 1) {
    if (tid < o) red[tid] = fmaxf(red[tid], red[tid + o]);
    __syncthreads();
  }
  if (tid == 0) gmax[k] = __float_as_uint(red[0]);
}

// K6: GEMM C = A (*) B^T with epilogue modes. Full 64 tiles, XCD swizzle.
// mode 0: C = acc
// mode 1: C = 2*Xadd - acc                      (Newton second half)
// mode 2: C = a3*acc + a2*Xadd + a1*Pex + a0*I  (deg-3 Chebyshev init, R13-validated)
// mode 3: mode 1, then double entries whose 128-tiles differ (pre-weights M for
//         the triangular-K quadratic form in vgemm; phi^T M phi only sees sym(M))
__global__ __launch_bounds__(256) void ntgemm_kernel(
    const u16* __restrict__ A, const u16* __restrict__ B,
    const u16* __restrict__ Xadd, const u16* __restrict__ Pex,
    const unsigned* __restrict__ gmax, u16* __restrict__ C, int mode)
{
  __shared__ u16 Als[128 * 64];
  __shared__ u16 Bls[128 * 64];
  const int k = blockIdx.y;
  const int ti = blockIdx.x & 7, tj = blockIdx.x >> 3;   // XCD swizzle (T1)
  const int i0 = ti * 128, j0 = tj * 128;
  const int tid = threadIdx.x;
  const int wid = tid >> 6, lane = tid & 63;
  const int wr = wid >> 1, wc = wid & 1;
  const size_t mb = (size_t)k * NIND * NIND;
  const u16* Ag = A + mb + (size_t)i0 * NIND;
  const u16* Bg = B + mb + (size_t)j0 * NIND;
  f32x4 acc[4][4];
  #pragma unroll
  for (int m = 0; m < 4; ++m)
    #pragma unroll
    for (int n = 0; n < 4; ++n) acc[m][n] = (f32x4){0.f, 0.f, 0.f, 0.f};
  for (int kb = 0; kb < NIND; kb += 64) {
    #pragma unroll
    for (int c = 0; c < 4; ++c) {
      int f = c * 256 + tid;
      int row = f >> 3, s = f & 7;
      int sc = (s ^ (row & 7)) << 3;
      gload16(Ag + (size_t)row * NIND + kb + sc, Als + ((c * 256 + wid * 64) << 3));
      gload16(Bg + (size_t)row * NIND + kb + sc, Bls + ((c * 256 + wid * 64) << 3));
    }
    __syncthreads();
    #pragma unroll
    for (int ks = 0; ks < 2; ++ks) {
      bf16x8 af[4], bfr[4];
      #pragma unroll
      for (int m = 0; m < 4; ++m) {
        int row = wr * 64 + m * 16 + (lane & 15);
        int kq = ks * 32 + (lane >> 4) * 8;
        int idx = (row * 64 + kq) ^ ((row & 7) << 3);
        af[m] = *(const bf16x8*)(&Als[idx]);
      }
      #pragma unroll
      for (int n = 0; n < 4; ++n) {
        int row = wc * 64 + n * 16 + (lane & 15);
        int kq = ks * 32 + (lane >> 4) * 8;
        int idx = (row * 64 + kq) ^ ((row & 7) << 3);
        bfr[n] = *(const bf16x8*)(&Bls[idx]);
      }
      #pragma unroll
      for (int m = 0; m < 4; ++m)
        #pragma unroll
        for (int n = 0; n < 4; ++n)
          acc[m][n] = __builtin_amdgcn_mfma_f32_16x16x32_bf16(af[m], bfr[n], acc[m][n], 0, 0, 0);
    }
    __syncthreads();
  }
  float a0 = 0.f, a1 = 0.f, a2 = 0.f, a3 = 0.f;
  if (mode == 2) {
    float G = __uint_as_float(gmax[k]) * 1.001f + 0.01f;
    if (G < 1.05f) G = 1.05f;
    float s = 1.0f + G, dd = G - 1.0f;
    float s2 = s * s, d2 = dd * dd;
    float D = 8.0f * s2 * s2 - 8.0f * d2 * s2 + d2 * d2;
    a3 = -128.0f / D;
    a2 = 256.0f * s / D;
    a1 = -(192.0f * s2 - 32.0f * d2) / D;
    a0 = (64.0f * s2 * s - 32.0f * d2 * s) / D;
  }
  #pragma unroll
  for (int m = 0; m < 4; ++m) {
    #pragma unroll
    for (int n = 0; n < 4; ++n) {
      #pragma unroll
      for (int r = 0; r < 4; ++r) {
        int gi = i0 + wr * 64 + m * 16 + (lane >> 4) * 4 + r;
        int gj = j0 + wc * 64 + n * 16 + (lane & 15);
        size_t idx = mb + (size_t)gi * NIND + gj;
        float v = acc[m][n][r];
        if (mode == 1 || mode == 3) {
          v = 2.0f * bflo((unsigned)Xadd[idx]) - v;
          if (mode == 3 && ti != tj) v *= 2.0f;
        } else if (mode == 2) {
          v = a3 * v + a2 * bflo((unsigned)Xadd[idx]) + a1 * bflo((unsigned)Pex[idx]);
          if (gi == gj) v += a0;
        }
        C[idx] = (u16)f2bf(v);
      }
    }
  }
}

// K7: balanced triangular variance GEMM. Block = (btile, pr); sequentially
// computes TWO row-blocks It0=pr and It1=7-pr, each with triangular K from
// It*128: (8-pr) + (1+pr) = 9 K-tiles per block, uniform. M tile-off-diag
// pre-doubled (mode 3) so triangular K gives phi^T sym(M) phi exactly.
__global__ __launch_bounds__(256) void vgemm_kernel(
    const u16* __restrict__ phiB, const u16* __restrict__ M,
    float* __restrict__ partial)
{
  __shared__ u16 Als[128 * 64];
  __shared__ u16 Bls[128 * 64];
  __shared__ float red[128][33];
  const int btile = blockIdx.x >> 2, pr = blockIdx.x & 3;
  const int k = blockIdx.y;
  const int b0 = btile * 128;
  const int tid = threadIdx.x;
  const int wid = tid >> 6, lane = tid & 63;
  const int wr = wid >> 1, wc = wid & 1;
  const int q = lane >> 4, l15 = lane & 15;
  const u16* Ag = phiB + (size_t)b0 * NIND;
  #pragma unroll
  for (int ph = 0; ph < 2; ++ph) {
    const int It = ph ? (7 - pr) : pr;
    const int i0 = It * 128;
    const u16* Bg = M + (size_t)k * NIND * NIND + (size_t)i0 * NIND;
    f32x4 acc[4][4];
    #pragma unroll
    for (int m = 0; m < 4; ++m)
      #pragma unroll
      for (int n = 0; n < 4; ++n) acc[m][n] = (f32x4){0.f, 0.f, 0.f, 0.f};
    for (int kb = i0; kb < NIND; kb += 64) {
      #pragma unroll
      for (int c = 0; c < 4; ++c) {
        int f = c * 256 + tid;
        int row = f >> 3, s = f & 7;
        int sc = (s ^ (row & 7)) << 3;
        gload16(Ag + (size_t)row * NIND + kb + sc, Als + ((c * 256 + wid * 64) << 3));
        gload16(Bg + (size_t)row * NIND + kb + sc, Bls + ((c * 256 + wid * 64) << 3));
      }
      __syncthreads();
      #pragma unroll
      for (int ks = 0; ks < 2; ++ks) {
        bf16x8 af[4], bfr[4];
        #pragma unroll
        for (int m = 0; m < 4; ++m) {
          int row = wr * 64 + m * 16 + l15;
          int kq = ks * 32 + q * 8;
          int idx = (row * 64 + kq) ^ ((row & 7) << 3);
          af[m] = *(const bf16x8*)(&Als[idx]);
        }
        #pragma unroll
        for (int n = 0; n < 4; ++n) {
          int row = wc * 64 + n * 16 + l15;
          int kq = ks * 32 + q * 8;
          int idx = (row * 64 + kq) ^ ((row & 7) << 3);
          bfr[n] = *(const bf16x8*)(&Bls[idx]);
        }
        #pragma unroll
        for (int m = 0; m < 4; ++m)
          #pragma unroll
          for (int n = 0; n < 4; ++n)
            acc[m][n] = __builtin_amdgcn_mfma_f32_16x16x32_bf16(af[m], bfr[n], acc[m][n], 0, 0, 0);
      }
      __syncthreads();
    }
    float vs[4][4] = {};
    #pragma unroll
    for (int m = 0; m < 4; ++m) {
      #pragma unroll
      for (int r = 0; r < 4; ++r) {
        int gb = b0 + wr * 64 + m * 16 + q * 4 + r;
        #pragma unroll
        for (int n = 0; n < 4; ++n) {
          int gi = i0 + wc * 64 + n * 16 + l15;
          float pv = bflo((unsigned)phiB[(size_t)gb * NIND + gi]);
          vs[m][r] += acc[m][n][r] * pv;
        }
      }
    }
    #pragma unroll
    for (int m = 0; m < 4; ++m)
      #pragma unroll
      for (int r = 0; r < 4; ++r)
        red[wr * 64 + m * 16 + q * 4 + r][wc * 16 + l15] = vs[m][r];
    __syncthreads();
    if (tid < 128) {
      float s = 0.f;
      #pragma unroll
      for (int t = 0; t < 32; ++t) s += red[tid][t];
      partial[((size_t)It * NCLS + k) * BATCH + b0 + tid] = s;
    }
    __syncthreads();
  }
}

// K8: out variances[b][k] = sum_It partial[It][k][b]
__global__ __launch_bounds__(256) void reduce_kernel(
    const float* __restrict__ partial, float* __restrict__ out)
{
  int t = blockIdx.x * 256 + threadIdx.x;
  int k = t >> 11, b = t & 2047;
  float s = 0.f;
  #pragma unroll
  for (int It = 0; It < 8; ++It)
    s += partial[((size_t)It * NCLS + k) * BATCH + b];
  out[(size_t)BATCH * NCLS + (size_t)b * NCLS + k] = s;
}

extern "C" void kernel_launch(void* const* d_in, const int* in_sizes, int n_in,
                              void* d_out, int out_size, void* d_ws, size_t ws_size,
                              hipStream_t stream)
{
  (void)in_sizes; (void)n_in; (void)ws_size; (void)out_size;
  const float* x   = (const float*)d_in[0];
  const float* rw  = (const float*)d_in[1];
  const float* rb  = (const float*)d_in[2];
  const float* bw  = (const float*)d_in[3];
  const float* bb  = (const float*)d_in[4];
  const float* prc = (const float*)d_in[5];
  float* out = (float*)d_out;
  char* ws = (char*)d_ws;
  size_t off = 0;
  auto alloc = [&](size_t bytes) -> void* {
    void* p = ws + off;
    off = (off + bytes + 255) & ~(size_t)255;
    return p;
  };
  const size_t MSZ = (size_t)NCLS * NIND * NIND * 2;   // 32MB bf16 matrix
  u16*   xB     = (u16*)  alloc((size_t)BATCH * FEAT * 2);
  u16*   rwT    = (u16*)  alloc((size_t)NIND * FEAT * 2);
  u16*   phiB   = (u16*)  alloc((size_t)BATCH * NIND * 2);
  u16*   phiTB  = (u16*)  alloc((size_t)NIND * BATCH * 2);
  float* wmat   = (float*)alloc((size_t)NCLS * BATCH * 4);
  u16*   Pb     = (u16*)  alloc(MSZ);
  unsigned* gbound = (unsigned*)alloc((size_t)NCLS * 4);
  float* rowAbs = (float*)alloc((size_t)NCLS * 16 * NIND * 4);   // 1MB
  float* partial = (float*)alloc((size_t)8 * NCLS * BATCH * 4);
  u16*   Xa     = (u16*)alloc(MSZ);
  u16*   B2     = (u16*)alloc(MSZ);
  u16*   BY     = (u16*)alloc(MSZ);
  // phiW (64MB) aliases Xa+B2 (contiguous): dead before G2 writes Xa.
  u16*   phiW   = Xa;

  xcast_kernel<<<dim3(BATCH * FEAT / 2048), 256, 0, stream>>>(x, xB);
  rwt_kernel<<<dim3(FEAT / 64, NIND / 64), 256, 0, stream>>>(rw, rwT);
  phimm_kernel<<<dim3(BATCH / 128, NIND / 128), 256, 0, stream>>>(xB, rwT, rb, phiB, phiTB);
  logits_kernel<<<dim3(BATCH / 16), 256, 0, stream>>>(phiB, bw, bb, out, wmat);
  scalew_kernel<<<dim3(1024, NCLS), 256, 0, stream>>>(phiTB, wmat, phiW);
  gram_kernel<<<dim3(64, NCLS), 256, 0, stream>>>(phiW, phiTB, prc, Pb, rowAbs);
  gersh2_kernel<<<dim3(NCLS), 256, 0, stream>>>(rowAbs, gbound);
  const dim3 gg(64, NCLS);
  // G1: BY = P^2
  ntgemm_kernel<<<gg, 256, 0, stream>>>(Pb, Pb, (u16*)nullptr, (u16*)nullptr,
                                        (unsigned*)nullptr, BY, 0);
  // G2: Xa = a3*P^3 + a2*P^2 + a1*P + a0*I  (cheb-3 fused into the P^3 GEMM)
  ntgemm_kernel<<<gg, 256, 0, stream>>>(BY, Pb, BY, Pb, gbound, Xa, 2);
  // G3+G4: one Newton iteration: BY = Xa*P ; B2 = (2*Xa - Xa*BY^T) with
  // tile-off-diagonal entries doubled (mode 3) for the triangular vgemm.
  ntgemm_kernel<<<gg, 256, 0, stream>>>(Xa, Pb, (u16*)nullptr, (u16*)nullptr,
                                        (unsigned*)nullptr, BY, 0);
  ntgemm_kernel<<<gg, 256, 0, stream>>>(Xa, BY, Xa, (u16*)nullptr,
                                        (unsigned*)nullptr, B2, 3);
  // variances: var_b = phi^T sym(M) phi via balanced triangular K (9 tiles/block)
  vgemm_kernel<<<dim3(64, NCLS), 256, 0, stream>>>(phiB, B2, partial);
  reduce_kernel<<<dim3(128), 256, 0, stream>>>(partial, out);
}

// Round 22
// 472.558 us; speedup vs baseline: 1.1510x; 1.0771x over previous
//
#include <hip/hip_runtime.h>
#include <hip/hip_bf16.h>

#define BATCH 2048
#define FEAT  768
#define NIND  1024
#define NCLS  16

typedef unsigned short u16;
typedef __attribute__((ext_vector_type(8))) __bf16 bf16x8;
typedef __attribute__((ext_vector_type(4))) float f32x4;

static __device__ __forceinline__ unsigned f2bf(float f) {
  unsigned u = __float_as_uint(f);
  unsigned r = ((u >> 16) & 1u) + 0x7FFFu;
  return (u + r) >> 16;                       // RNE bf16 in low 16 bits
}
static __device__ __forceinline__ float bflo(unsigned x) {
  return __uint_as_float((x & 0xFFFFu) << 16);
}
static __device__ __forceinline__ float bfhi(unsigned x) {
  return __uint_as_float(x & 0xFFFF0000u);
}

// async 16B global->LDS (LDS dest = wave-uniform base + lane*16)
static __device__ __forceinline__ void gload16(const u16* g, u16* l) {
  __builtin_amdgcn_global_load_lds(
      (const __attribute__((address_space(1))) void*)g,
      (__attribute__((address_space(3))) void*)l, 16, 0, 0);
}

// pack 8 bf16 (as uint4) scaled by wv[0..7] back to 8 bf16 (uint4)
static __device__ __forceinline__ uint4 scale8(uint4 v, const float* wv) {
  unsigned out[4];
  const unsigned* in = (const unsigned*)&v;
  #pragma unroll
  for (int i = 0; i < 4; ++i) {
    float lo = bflo(in[i]) * wv[2*i];
    float hi = bfhi(in[i]) * wv[2*i+1];
    __hip_bfloat162 pk = __float22bfloat162_rn(float2{lo, hi});
    out[i] = *(unsigned*)&pk;
  }
  return uint4{out[0], out[1], out[2], out[3]};
}

// K0a: xB = bf16(x), elementwise
__global__ __launch_bounds__(256) void xcast_kernel(
    const float* __restrict__ x, u16* __restrict__ xB)
{
  size_t f = ((size_t)blockIdx.x * 256 + threadIdx.x) * 8;
  float4 a = *(const float4*)(x + f);
  float4 b = *(const float4*)(x + f + 4);
  uint4 o;
  o.x = (f2bf(a.x) & 0xFFFFu) | (f2bf(a.y) << 16);
  o.y = (f2bf(a.z) & 0xFFFFu) | (f2bf(a.w) << 16);
  o.z = (f2bf(b.x) & 0xFFFFu) | (f2bf(b.y) << 16);
  o.w = (f2bf(b.z) & 0xFFFFu) | (f2bf(b.w) << 16);
  *(uint4*)(xB + f) = o;
}

// K0b: rwT[i][k] = bf16(rw[k][i])  (LDS-tiled transpose)
__global__ __launch_bounds__(256) void rwt_kernel(
    const float* __restrict__ rw, u16* __restrict__ rwT)
{
  __shared__ float ts[64][65];
  const int k0 = blockIdx.x * 64, i0 = blockIdx.y * 64;
  const int tid = threadIdx.x;
  #pragma unroll
  for (int t = 0; t < 4; ++t) {
    int f = t * 256 + tid;
    int r = f >> 4, c4 = (f & 15) << 2;
    *(float4*)(&ts[r][c4]) = *(const float4*)(rw + (size_t)(k0 + r) * NIND + i0 + c4);
  }
  __syncthreads();
  #pragma unroll
  for (int t = 0; t < 4; ++t) {
    int f = t * 256 + tid;
    int r = f >> 4, c4 = (f & 15) << 2;   // r = i-local, c4 = k-local base
    uint2 o;
    o.x = (f2bf(ts[c4+0][r]) & 0xFFFFu) | (f2bf(ts[c4+1][r]) << 16);
    o.y = (f2bf(ts[c4+2][r]) & 0xFFFFu) | (f2bf(ts[c4+3][r]) << 16);
    *(uint2*)(rwT + (size_t)(i0 + r) * FEAT + k0 + c4) = o;
  }
}

// K1: MFMA phi. phiB[b][i], phiTB[i][b] = bf16(SC*cos(2*(x@W+b))). K=768.
__global__ __launch_bounds__(256) void phimm_kernel(
    const u16* __restrict__ xB, const u16* __restrict__ rwT,
    const float* __restrict__ rb, u16* __restrict__ phiB,
    u16* __restrict__ phiTB)
{
  __shared__ u16 sh[128 * 128];      // staging (2x 128x64) then transpose tile
  u16* Als = sh;
  u16* Bls = sh + 8192;
  const int b0 = blockIdx.x * 128, i0 = blockIdx.y * 128;
  const int tid = threadIdx.x;
  const int wid = tid >> 6, lane = tid & 63;
  const int wr = wid >> 1, wc = wid & 1;
  const u16* Ag = xB + (size_t)b0 * FEAT;
  const u16* Bg = rwT + (size_t)i0 * FEAT;
  f32x4 acc[4][4];
  #pragma unroll
  for (int m = 0; m < 4; ++m)
    #pragma unroll
    for (int n = 0; n < 4; ++n) acc[m][n] = (f32x4){0.f, 0.f, 0.f, 0.f};
  for (int kb = 0; kb < FEAT; kb += 64) {
    #pragma unroll
    for (int c = 0; c < 4; ++c) {
      int f = c * 256 + tid;
      int row = f >> 3, s = f & 7;
      int sc = (s ^ (row & 7)) << 3;
      gload16(Ag + (size_t)row * FEAT + kb + sc, Als + ((c * 256 + wid * 64) << 3));
      gload16(Bg + (size_t)row * FEAT + kb + sc, Bls + ((c * 256 + wid * 64) << 3));
    }
    __syncthreads();
    #pragma unroll
    for (int ks = 0; ks < 2; ++ks) {
      bf16x8 af[4], bfr[4];
      #pragma unroll
      for (int m = 0; m < 4; ++m) {
        int row = wr * 64 + m * 16 + (lane & 15);
        int kq = ks * 32 + (lane >> 4) * 8;
        int idx = (row * 64 + kq) ^ ((row & 7) << 3);
        af[m] = *(const bf16x8*)(&Als[idx]);
      }
      #pragma unroll
      for (int n = 0; n < 4; ++n) {
        int row = wc * 64 + n * 16 + (lane & 15);
        int kq = ks * 32 + (lane >> 4) * 8;
        int idx = (row * 64 + kq) ^ ((row & 7) << 3);
        bfr[n] = *(const bf16x8*)(&Bls[idx]);
      }
      #pragma unroll
      for (int m = 0; m < 4; ++m)
        #pragma unroll
        for (int n = 0; n < 4; ++n)
          acc[m][n] = __builtin_amdgcn_mfma_f32_16x16x32_bf16(af[m], bfr[n], acc[m][n], 0, 0, 0);
    }
    __syncthreads();
  }
  const float SC = 0.04419417382415922f;   // sqrt(2/1024)
  float rbl[4];
  #pragma unroll
  for (int n = 0; n < 4; ++n) rbl[n] = rb[i0 + wc * 64 + n * 16 + (lane & 15)];
  #pragma unroll
  for (int m = 0; m < 4; ++m) {
    #pragma unroll
    for (int n = 0; n < 4; ++n) {
      #pragma unroll
      for (int r = 0; r < 4; ++r) {
        int lb = wr * 64 + m * 16 + (lane >> 4) * 4 + r;
        int li = wc * 64 + n * 16 + (lane & 15);
        float proj = 2.0f * (acc[m][n][r] + rbl[n]);
        u16 bv = (u16)f2bf(SC * cosf(proj));
        phiB[(size_t)(b0 + lb) * NIND + i0 + li] = bv;
        int idx = (li * 128 + lb) ^ ((li & 7) << 3);
        sh[idx] = bv;
      }
    }
  }
  __syncthreads();
  #pragma unroll
  for (int t = 0; t < 8; ++t) {
    int f = t * 256 + tid;             // 2048 uint4-slots over 128x128 u16
    int li = f >> 4, c8 = (f & 15) << 3;
    int idx = (li * 128 + c8) ^ ((li & 7) << 3);
    uint4 v = *(const uint4*)(&sh[idx]);
    *(uint4*)(phiTB + (size_t)(i0 + li) * BATCH + b0 + c8) = v;
  }
}

// K2: logits from phiB (bf16), 16 batch rows per block, thread = (row, class)
__global__ __launch_bounds__(256) void logits_kernel(
    const u16* __restrict__ phiB, const float* __restrict__ bw,
    const float* __restrict__ bbias, float* __restrict__ out,
    float* __restrict__ wmat)
{
  __shared__ float ph[16][132];
  __shared__ float bwl[16][132];
  __shared__ float lg[16][17];
  const int b0 = blockIdx.x * 16;
  const int tid = threadIdx.x;
  const int bl = tid & 15, kq = tid >> 4;
  float acc = 0.f;
  for (int kb = 0; kb < NIND; kb += 128) {
    {
      int row = tid >> 4, c8 = (tid & 15) << 3;
      uint4 v = *(const uint4*)(phiB + (size_t)(b0 + row) * NIND + kb + c8);
      const unsigned* u = (const unsigned*)&v;
      #pragma unroll
      for (int j = 0; j < 4; ++j) {
        ph[row][c8 + 2*j]     = bflo(u[j]);
        ph[row][c8 + 2*j + 1] = bfhi(u[j]);
      }
    }
    #pragma unroll
    for (int t = 0; t < 2; ++t) {
      int f = t * 256 + tid;
      int row = f >> 5, c4 = (f & 31) << 2;
      *(float4*)(&bwl[row][c4]) = *(const float4*)(bw + (size_t)row * NIND + kb + c4);
    }
    __syncthreads();
    #pragma unroll 8
    for (int q = 0; q < 128; q += 4) {
      float4 a = *(const float4*)(&ph[bl][q]);
      float4 b4 = *(const float4*)(&bwl[kq][q]);
      acc += a.x*b4.x + a.y*b4.y + a.z*b4.z + a.w*b4.w;
    }
    __syncthreads();
  }
  float v = acc + bbias[kq];
  lg[bl][kq] = v;
  out[(size_t)(b0 + bl) * NCLS + kq] = v;
  __syncthreads();
  if (tid < 16) {
    float mx = -1e30f;
    #pragma unroll
    for (int k = 0; k < 16; ++k) mx = fmaxf(mx, lg[tid][k]);
    float s = 0.f, ex[16];
    #pragma unroll
    for (int k = 0; k < 16; ++k) { ex[k] = expf(lg[tid][k] - mx); s += ex[k]; }
    float inv = 1.0f / s;
    #pragma unroll
    for (int k = 0; k < 16; ++k) {
      float p = ex[k] * inv;
      wmat[(size_t)k * BATCH + b0 + tid] = p * (1.0f - p);
    }
  }
}

// K2b: phiW[k][i][b] = bf16(wmat[k][b] * phi[i][b])  (from bf16 phiTB)
__global__ __launch_bounds__(256) void scalew_kernel(
    const u16* __restrict__ phiTB, const float* __restrict__ wmat,
    u16* __restrict__ phiW)
{
  const int k = blockIdx.y;
  size_t flat = ((size_t)blockIdx.x * 256 + threadIdx.x) * 8;
  int b = (int)(flat & 2047);
  uint4 pv = *(const uint4*)(phiTB + flat);
  float4 w0 = *(const float4*)(wmat + (size_t)k * BATCH + b);
  float4 w1 = *(const float4*)(wmat + (size_t)k * BATCH + b + 4);
  float wv[8] = {w0.x, w0.y, w0.z, w0.w, w1.x, w1.y, w1.z, w1.w};
  *(uint4*)(phiW + (size_t)k * NIND * BATCH + flat) = scale8(pv, wv);
}

// K3: MFMA bf16 gram -> Pb bf16. FULL 64-tile grid (4 blocks/CU; R17-verified).
// XCD = ti. Epilogue also emits per-row |P| partials (Gershgorin fold).
__global__ __launch_bounds__(256) void gram_kernel(
    const u16* __restrict__ phiW, const u16* __restrict__ phiTB,
    const float* __restrict__ prec, u16* __restrict__ Pb,
    float* __restrict__ rowAbs)
{
  __shared__ u16 Als[128 * 64];
  __shared__ u16 Bls[128 * 64];
  const int ti = blockIdx.x & 7, tj = blockIdx.x >> 3;   // XCD = ti
  const int k = blockIdx.y;
  const int i0 = ti * 128, j0 = tj * 128;
  const int tid = threadIdx.x;
  const int wid = tid >> 6, lane = tid & 63;
  const int wr = wid >> 1, wc = wid & 1;
  const u16* Ag = phiW + (size_t)k * NIND * BATCH + (size_t)i0 * BATCH;
  const u16* Bg = phiTB + (size_t)j0 * BATCH;
  f32x4 acc[4][4];
  #pragma unroll
  for (int m = 0; m < 4; ++m)
    #pragma unroll
    for (int n = 0; n < 4; ++n) acc[m][n] = (f32x4){0.f, 0.f, 0.f, 0.f};
  for (int b0 = 0; b0 < BATCH; b0 += 64) {
    #pragma unroll
    for (int c = 0; c < 4; ++c) {
      int f = c * 256 + tid;
      int row = f >> 3, s = f & 7;
      int sc = (s ^ (row & 7)) << 3;
      gload16(Ag + (size_t)row * BATCH + b0 + sc, Als + ((c * 256 + wid * 64) << 3));
      gload16(Bg + (size_t)row * BATCH + b0 + sc, Bls + ((c * 256 + wid * 64) << 3));
    }
    __syncthreads();
    #pragma unroll
    for (int ks = 0; ks < 2; ++ks) {
      bf16x8 af[4], bfr[4];
      #pragma unroll
      for (int m = 0; m < 4; ++m) {
        int row = wr * 64 + m * 16 + (lane & 15);
        int kb = ks * 32 + (lane >> 4) * 8;
        int idx = (row * 64 + kb) ^ ((row & 7) << 3);
        af[m] = *(const bf16x8*)(&Als[idx]);
      }
      #pragma unroll
      for (int n = 0; n < 4; ++n) {
        int row = wc * 64 + n * 16 + (lane & 15);
        int kb = ks * 32 + (lane >> 4) * 8;
        int idx = (row * 64 + kb) ^ ((row & 7) << 3);
        bfr[n] = *(const bf16x8*)(&Bls[idx]);
      }
      #pragma unroll
      for (int m = 0; m < 4; ++m)
        #pragma unroll
        for (int n = 0; n < 4; ++n)
          acc[m][n] = __builtin_amdgcn_mfma_f32_16x16x32_bf16(af[m], bfr[n], acc[m][n], 0, 0, 0);
    }
    __syncthreads();
  }
  const size_t kb2 = (size_t)k * NIND * NIND;
  float sabs[4][4];
  #pragma unroll
  for (int m = 0; m < 4; ++m)
    #pragma unroll
    for (int r = 0; r < 4; ++r) sabs[m][r] = 0.f;
  #pragma unroll
  for (int m = 0; m < 4; ++m) {
    #pragma unroll
    for (int n = 0; n < 4; ++n) {
      #pragma unroll
      for (int r = 0; r < 4; ++r) {
        int gi = i0 + wr * 64 + m * 16 + (lane >> 4) * 4 + r;
        int gj = j0 + wc * 64 + n * 16 + (lane & 15);
        size_t idx = kb2 + (size_t)gi * NIND + gj;
        float v = acc[m][n][r] + prec[idx];
        u16 bv = (u16)f2bf(v);
        Pb[idx] = bv;
        sabs[m][r] += fabsf(__uint_as_float((unsigned)bv << 16));
      }
    }
  }
  float* rp = rowAbs + ((size_t)k * 16 + tj * 2 + wc) * NIND + i0;
  #pragma unroll
  for (int m = 0; m < 4; ++m) {
    #pragma unroll
    for (int r = 0; r < 4; ++r) {
      float s = sabs[m][r];
      s += __shfl_xor(s, 1);
      s += __shfl_xor(s, 2);
      s += __shfl_xor(s, 4);
      s += __shfl_xor(s, 8);
      if ((lane & 15) == 0)
        rp[wr * 64 + m * 16 + (lane >> 4) * 4 + r] = s;
    }
  }
}

// K4: gersh2 -- G[k] = max_row sum over the 16 rowAbs slices (1MB total read)
__global__ __launch_bounds__(256) void gersh2_kernel(
    const float* __restrict__ rowAbs, unsigned* __restrict__ gmax)
{
  __shared__ float red[256];
  const int k = blockIdx.x, tid = threadIdx.x;
  const float* base = rowAbs + (size_t)k * 16 * NIND;
  float mx = 0.f;
  for (int row = tid; row < NIND; row += 256) {
    float s = 0.f;
    #pragma unroll
    for (int sl = 0; sl < 16; ++sl) s += base[(size_t)sl * NIND + row];
    mx = fmaxf(mx, s);
  }
  red[tid] = mx;
  __syncthreads();
  for (int o = 128; o > 0; o >>= 1) {
    if (tid < o) red[tid] = fmaxf(red[tid], red[tid + o]);
    __syncthreads();
  }
  if (tid == 0) gmax[k] = __float_as_uint(red[0]);
}

// K6 v2: 256x128-tile GEMM C = A (*) B^T (512 threads, 8 waves as 4x2; each
// wave owns 64x64 -> per-wave code identical to the 128x128 version, but
// 25% less L2/L3 traffic per output). Epilogue modes as before; mode 3's
// doubling is the general per-element 128-tile test (vgemm contract kept).
__global__ __launch_bounds__(512) void ntgemm_kernel(
    const u16* __restrict__ A, const u16* __restrict__ B,
    const u16* __restrict__ Xadd, const u16* __restrict__ Pex,
    const unsigned* __restrict__ gmax, u16* __restrict__ C, int mode)
{
  __shared__ u16 Als[256 * 64];   // 32KB
  __shared__ u16 Bls[128 * 64];   // 16KB
  const int k = blockIdx.y;
  const int tj = blockIdx.x & 7, ti = blockIdx.x >> 3;   // XCD = tj (B-panel local)
  const int i0 = ti * 256, j0 = tj * 128;
  const int tid = threadIdx.x;
  const int wid = tid >> 6, lane = tid & 63;
  const int wr = wid >> 1, wc = wid & 1;    // wr in [0,4), wc in [0,2)
  const size_t mb = (size_t)k * NIND * NIND;
  const u16* Ag = A + mb + (size_t)i0 * NIND;
  const u16* Bg = B + mb + (size_t)j0 * NIND;
  f32x4 acc[4][4];
  #pragma unroll
  for (int m = 0; m < 4; ++m)
    #pragma unroll
    for (int n = 0; n < 4; ++n) acc[m][n] = (f32x4){0.f, 0.f, 0.f, 0.f};
  for (int kb = 0; kb < NIND; kb += 64) {
    #pragma unroll
    for (int c = 0; c < 4; ++c) {        // A: 2048 slots (256 rows x 8 chunks)
      int f = c * 512 + tid;
      int row = f >> 3, s = f & 7;
      int sc = (s ^ (row & 7)) << 3;
      gload16(Ag + (size_t)row * NIND + kb + sc, Als + ((c * 512 + wid * 64) << 3));
    }
    #pragma unroll
    for (int c = 0; c < 2; ++c) {        // B: 1024 slots (128 rows x 8 chunks)
      int f = c * 512 + tid;
      int row = f >> 3, s = f & 7;
      int sc = (s ^ (row & 7)) << 3;
      gload16(Bg + (size_t)row * NIND + kb + sc, Bls + ((c * 512 + wid * 64) << 3));
    }
    __syncthreads();
    #pragma unroll
    for (int ks = 0; ks < 2; ++ks) {
      bf16x8 af[4], bfr[4];
      #pragma unroll
      for (int m = 0; m < 4; ++m) {
        int row = wr * 64 + m * 16 + (lane & 15);      // [0,256)
        int kq = ks * 32 + (lane >> 4) * 8;
        int idx = (row * 64 + kq) ^ ((row & 7) << 3);
        af[m] = *(const bf16x8*)(&Als[idx]);
      }
      #pragma unroll
      for (int n = 0; n < 4; ++n) {
        int row = wc * 64 + n * 16 + (lane & 15);      // [0,128)
        int kq = ks * 32 + (lane >> 4) * 8;
        int idx = (row * 64 + kq) ^ ((row & 7) << 3);
        bfr[n] = *(const bf16x8*)(&Bls[idx]);
      }
      #pragma unroll
      for (int m = 0; m < 4; ++m)
        #pragma unroll
        for (int n = 0; n < 4; ++n)
          acc[m][n] = __builtin_amdgcn_mfma_f32_16x16x32_bf16(af[m], bfr[n], acc[m][n], 0, 0, 0);
    }
    __syncthreads();
  }
  float a0 = 0.f, a1 = 0.f, a2 = 0.f, a3 = 0.f;
  if (mode == 2) {
    float G = __uint_as_float(gmax[k]) * 1.001f + 0.01f;
    if (G < 1.05f) G = 1.05f;
    float s = 1.0f + G, dd = G - 1.0f;
    float s2 = s * s, d2 = dd * dd;
    float D = 8.0f * s2 * s2 - 8.0f * d2 * s2 + d2 * d2;
    a3 = -128.0f / D;
    a2 = 256.0f * s / D;
    a1 = -(192.0f * s2 - 32.0f * d2) / D;
    a0 = (64.0f * s2 * s - 32.0f * d2 * s) / D;
  }
  #pragma unroll
  for (int m = 0; m < 4; ++m) {
    #pragma unroll
    for (int n = 0; n < 4; ++n) {
      #pragma unroll
      for (int r = 0; r < 4; ++r) {
        int gi = i0 + wr * 64 + m * 16 + (lane >> 4) * 4 + r;
        int gj = j0 + wc * 64 + n * 16 + (lane & 15);
        size_t idx = mb + (size_t)gi * NIND + gj;
        float v = acc[m][n][r];
        if (mode == 1 || mode == 3) {
          v = 2.0f * bflo((unsigned)Xadd[idx]) - v;
          if (mode == 3 && (gi >> 7) != (gj >> 7)) v *= 2.0f;
        } else if (mode == 2) {
          v = a3 * v + a2 * bflo((unsigned)Xadd[idx]) + a1 * bflo((unsigned)Pex[idx]);
          if (gi == gj) v += a0;
        }
        C[idx] = (u16)f2bf(v);
      }
    }
  }
}

// K7: balanced triangular variance GEMM. Block = (btile, pr); sequentially
// computes TWO row-blocks It0=pr and It1=7-pr, each with triangular K from
// It*128: (8-pr) + (1+pr) = 9 K-tiles per block, uniform. M tile-off-diag
// pre-doubled (mode 3) so triangular K gives phi^T sym(M) phi exactly.
__global__ __launch_bounds__(256) void vgemm_kernel(
    const u16* __restrict__ phiB, const u16* __restrict__ M,
    float* __restrict__ partial)
{
  __shared__ u16 Als[128 * 64];
  __shared__ u16 Bls[128 * 64];
  __shared__ float red[128][33];
  const int btile = blockIdx.x >> 2, pr = blockIdx.x & 3;
  const int k = blockIdx.y;
  const int b0 = btile * 128;
  const int tid = threadIdx.x;
  const int wid = tid >> 6, lane = tid & 63;
  const int wr = wid >> 1, wc = wid & 1;
  const int q = lane >> 4, l15 = lane & 15;
  const u16* Ag = phiB + (size_t)b0 * NIND;
  #pragma unroll
  for (int ph = 0; ph < 2; ++ph) {
    const int It = ph ? (7 - pr) : pr;
    const int i0 = It * 128;
    const u16* Bg = M + (size_t)k * NIND * NIND + (size_t)i0 * NIND;
    f32x4 acc[4][4];
    #pragma unroll
    for (int m = 0; m < 4; ++m)
      #pragma unroll
      for (int n = 0; n < 4; ++n) acc[m][n] = (f32x4){0.f, 0.f, 0.f, 0.f};
    for (int kb = i0; kb < NIND; kb += 64) {
      #pragma unroll
      for (int c = 0; c < 4; ++c) {
        int f = c * 256 + tid;
        int row = f >> 3, s = f & 7;
        int sc = (s ^ (row & 7)) << 3;
        gload16(Ag + (size_t)row * NIND + kb + sc, Als + ((c * 256 + wid * 64) << 3));
        gload16(Bg + (size_t)row * NIND + kb + sc, Bls + ((c * 256 + wid * 64) << 3));
      }
      __syncthreads();
      #pragma unroll
      for (int ks = 0; ks < 2; ++ks) {
        bf16x8 af[4], bfr[4];
        #pragma unroll
        for (int m = 0; m < 4; ++m) {
          int row = wr * 64 + m * 16 + l15;
          int kq = ks * 32 + q * 8;
          int idx = (row * 64 + kq) ^ ((row & 7) << 3);
          af[m] = *(const bf16x8*)(&Als[idx]);
        }
        #pragma unroll
        for (int n = 0; n < 4; ++n) {
          int row = wc * 64 + n * 16 + l15;
          int kq = ks * 32 + q * 8;
          int idx = (row * 64 + kq) ^ ((row & 7) << 3);
          bfr[n] = *(const bf16x8*)(&Bls[idx]);
        }
        #pragma unroll
        for (int m = 0; m < 4; ++m)
          #pragma unroll
          for (int n = 0; n < 4; ++n)
            acc[m][n] = __builtin_amdgcn_mfma_f32_16x16x32_bf16(af[m], bfr[n], acc[m][n], 0, 0, 0);
      }
      __syncthreads();
    }
    float vs[4][4] = {};
    #pragma unroll
    for (int m = 0; m < 4; ++m) {
      #pragma unroll
      for (int r = 0; r < 4; ++r) {
        int gb = b0 + wr * 64 + m * 16 + q * 4 + r;
        #pragma unroll
        for (int n = 0; n < 4; ++n) {
          int gi = i0 + wc * 64 + n * 16 + l15;
          float pv = bflo((unsigned)phiB[(size_t)gb * NIND + gi]);
          vs[m][r] += acc[m][n][r] * pv;
        }
      }
    }
    #pragma unroll
    for (int m = 0; m < 4; ++m)
      #pragma unroll
      for (int r = 0; r < 4; ++r)
        red[wr * 64 + m * 16 + q * 4 + r][wc * 16 + l15] = vs[m][r];
    __syncthreads();
    if (tid < 128) {
      float s = 0.f;
      #pragma unroll
      for (int t = 0; t < 32; ++t) s += red[tid][t];
      partial[((size_t)It * NCLS + k) * BATCH + b0 + tid] = s;
    }
    __syncthreads();
  }
}

// K8: out variances[b][k] = sum_It partial[It][k][b]
__global__ __launch_bounds__(256) void reduce_kernel(
    const float* __restrict__ partial, float* __restrict__ out)
{
  int t = blockIdx.x * 256 + threadIdx.x;
  int k = t >> 11, b = t & 2047;
  float s = 0.f;
  #pragma unroll
  for (int It = 0; It < 8; ++It)
    s += partial[((size_t)It * NCLS + k) * BATCH + b];
  out[(size_t)BATCH * NCLS + (size_t)b * NCLS + k] = s;
}

extern "C" void kernel_launch(void* const* d_in, const int* in_sizes, int n_in,
                              void* d_out, int out_size, void* d_ws, size_t ws_size,
                              hipStream_t stream)
{
  (void)in_sizes; (void)n_in; (void)ws_size; (void)out_size;
  const float* x   = (const float*)d_in[0];
  const float* rw  = (const float*)d_in[1];
  const float* rb  = (const float*)d_in[2];
  const float* bw  = (const float*)d_in[3];
  const float* bb  = (const float*)d_in[4];
  const float* prc = (const float*)d_in[5];
  float* out = (float*)d_out;
  char* ws = (char*)d_ws;
  size_t off = 0;
  auto alloc = [&](size_t bytes) -> void* {
    void* p = ws + off;
    off = (off + bytes + 255) & ~(size_t)255;
    return p;
  };
  const size_t MSZ = (size_t)NCLS * NIND * NIND * 2;   // 32MB bf16 matrix
  u16*   xB     = (u16*)  alloc((size_t)BATCH * FEAT * 2);
  u16*   rwT    = (u16*)  alloc((size_t)NIND * FEAT * 2);
  u16*   phiB   = (u16*)  alloc((size_t)BATCH * NIND * 2);
  u16*   phiTB  = (u16*)  alloc((size_t)NIND * BATCH * 2);
  float* wmat   = (float*)alloc((size_t)NCLS * BATCH * 4);
  u16*   Pb     = (u16*)  alloc(MSZ);
  unsigned* gbound = (unsigned*)alloc((size_t)NCLS * 4);
  float* rowAbs = (float*)alloc((size_t)NCLS * 16 * NIND * 4);   // 1MB
  float* partial = (float*)alloc((size_t)8 * NCLS * BATCH * 4);
  u16*   Xa     = (u16*)alloc(MSZ);
  u16*   B2     = (u16*)alloc(MSZ);
  u16*   BY     = (u16*)alloc(MSZ);
  // phiW (64MB) aliases Xa+B2 (contiguous): dead before G2 writes Xa.
  u16*   phiW   = Xa;

  xcast_kernel<<<dim3(BATCH * FEAT / 2048), 256, 0, stream>>>(x, xB);
  rwt_kernel<<<dim3(FEAT / 64, NIND / 64), 256, 0, stream>>>(rw, rwT);
  phimm_kernel<<<dim3(BATCH / 128, NIND / 128), 256, 0, stream>>>(xB, rwT, rb, phiB, phiTB);
  logits_kernel<<<dim3(BATCH / 16), 256, 0, stream>>>(phiB, bw, bb, out, wmat);
  scalew_kernel<<<dim3(1024, NCLS), 256, 0, stream>>>(phiTB, wmat, phiW);
  gram_kernel<<<dim3(64, NCLS), 256, 0, stream>>>(phiW, phiTB, prc, Pb, rowAbs);
  gersh2_kernel<<<dim3(NCLS), 256, 0, stream>>>(rowAbs, gbound);
  const dim3 gg(32, NCLS);
  // G1: BY = P^2
  ntgemm_kernel<<<gg, 512, 0, stream>>>(Pb, Pb, (u16*)nullptr, (u16*)nullptr,
                                        (unsigned*)nullptr, BY, 0);
  // G2: Xa = a3*P^3 + a2*P^2 + a1*P + a0*I  (cheb-3 fused into the P^3 GEMM)
  ntgemm_kernel<<<gg, 512, 0, stream>>>(BY, Pb, BY, Pb, gbound, Xa, 2);
  // G3+G4: one Newton iteration: BY = Xa*P ; B2 = (2*Xa - Xa*BY^T) with
  // 128-tile-off-diagonal entries doubled (mode 3) for the triangular vgemm.
  ntgemm_kernel<<<gg, 512, 0, stream>>>(Xa, Pb, (u16*)nullptr, (u16*)nullptr,
                                        (unsigned*)nullptr, BY, 0);
  ntgemm_kernel<<<gg, 512, 0, stream>>>(Xa, BY, Xa, (u16*)nullptr,
                                        (unsigned*)nullptr, B2, 3);
  // variances: var_b = phi^T sym(M) phi via balanced triangular K (9 tiles/block)
  vgemm_kernel<<<dim3(64, NCLS), 256, 0, stream>>>(phiB, B2, partial);
  reduce_kernel<<<dim3(128), 256, 0, stream>>>(partial, out);
}

// Round 23
// 465.717 us; speedup vs baseline: 1.1679x; 1.0147x over previous
//
#include <hip/hip_runtime.h>
#include <hip/hip_bf16.h>

#define BATCH 2048
#define FEAT  768
#define NIND  1024
#define NCLS  16

typedef unsigned short u16;
typedef __attribute__((ext_vector_type(8))) __bf16 bf16x8;
typedef __attribute__((ext_vector_type(4))) float f32x4;

static __device__ __forceinline__ unsigned f2bf(float f) {
  unsigned u = __float_as_uint(f);
  unsigned r = ((u >> 16) & 1u) + 0x7FFFu;
  return (u + r) >> 16;                       // RNE bf16 in low 16 bits
}
static __device__ __forceinline__ float bflo(unsigned x) {
  return __uint_as_float((x & 0xFFFFu) << 16);
}
static __device__ __forceinline__ float bfhi(unsigned x) {
  return __uint_as_float(x & 0xFFFF0000u);
}

// async 16B global->LDS (LDS dest = wave-uniform base + lane*16)
static __device__ __forceinline__ void gload16(const u16* g, u16* l) {
  __builtin_amdgcn_global_load_lds(
      (const __attribute__((address_space(1))) void*)g,
      (__attribute__((address_space(3))) void*)l, 16, 0, 0);
}

// pack 8 bf16 (as uint4) scaled by wv[0..7] back to 8 bf16 (uint4)
static __device__ __forceinline__ uint4 scale8(uint4 v, const float* wv) {
  unsigned out[4];
  const unsigned* in = (const unsigned*)&v;
  #pragma unroll
  for (int i = 0; i < 4; ++i) {
    float lo = bflo(in[i]) * wv[2*i];
    float hi = bfhi(in[i]) * wv[2*i+1];
    __hip_bfloat162 pk = __float22bfloat162_rn(float2{lo, hi});
    out[i] = *(unsigned*)&pk;
  }
  return uint4{out[0], out[1], out[2], out[3]};
}

// K0a: xB = bf16(x), elementwise
__global__ __launch_bounds__(256) void xcast_kernel(
    const float* __restrict__ x, u16* __restrict__ xB)
{
  size_t f = ((size_t)blockIdx.x * 256 + threadIdx.x) * 8;
  float4 a = *(const float4*)(x + f);
  float4 b = *(const float4*)(x + f + 4);
  uint4 o;
  o.x = (f2bf(a.x) & 0xFFFFu) | (f2bf(a.y) << 16);
  o.y = (f2bf(a.z) & 0xFFFFu) | (f2bf(a.w) << 16);
  o.z = (f2bf(b.x) & 0xFFFFu) | (f2bf(b.y) << 16);
  o.w = (f2bf(b.z) & 0xFFFFu) | (f2bf(b.w) << 16);
  *(uint4*)(xB + f) = o;
}

// K0b: rwT[i][k] = bf16(rw[k][i])  (LDS-tiled transpose)
__global__ __launch_bounds__(256) void rwt_kernel(
    const float* __restrict__ rw, u16* __restrict__ rwT)
{
  __shared__ float ts[64][65];
  const int k0 = blockIdx.x * 64, i0 = blockIdx.y * 64;
  const int tid = threadIdx.x;
  #pragma unroll
  for (int t = 0; t < 4; ++t) {
    int f = t * 256 + tid;
    int r = f >> 4, c4 = (f & 15) << 2;
    *(float4*)(&ts[r][c4]) = *(const float4*)(rw + (size_t)(k0 + r) * NIND + i0 + c4);
  }
  __syncthreads();
  #pragma unroll
  for (int t = 0; t < 4; ++t) {
    int f = t * 256 + tid;
    int r = f >> 4, c4 = (f & 15) << 2;   // r = i-local, c4 = k-local base
    uint2 o;
    o.x = (f2bf(ts[c4+0][r]) & 0xFFFFu) | (f2bf(ts[c4+1][r]) << 16);
    o.y = (f2bf(ts[c4+2][r]) & 0xFFFFu) | (f2bf(ts[c4+3][r]) << 16);
    *(uint2*)(rwT + (size_t)(i0 + r) * FEAT + k0 + c4) = o;
  }
}

// K1: MFMA phi. phiB[b][i], phiTB[i][b] = bf16(SC*cos(2*(x@W+b))). K=768.
__global__ __launch_bounds__(256) void phimm_kernel(
    const u16* __restrict__ xB, const u16* __restrict__ rwT,
    const float* __restrict__ rb, u16* __restrict__ phiB,
    u16* __restrict__ phiTB)
{
  __shared__ u16 sh[128 * 128];      // staging (2x 128x64) then transpose tile
  u16* Als = sh;
  u16* Bls = sh + 8192;
  const int b0 = blockIdx.x * 128, i0 = blockIdx.y * 128;
  const int tid = threadIdx.x;
  const int wid = tid >> 6, lane = tid & 63;
  const int wr = wid >> 1, wc = wid & 1;
  const u16* Ag = xB + (size_t)b0 * FEAT;
  const u16* Bg = rwT + (size_t)i0 * FEAT;
  f32x4 acc[4][4];
  #pragma unroll
  for (int m = 0; m < 4; ++m)
    #pragma unroll
    for (int n = 0; n < 4; ++n) acc[m][n] = (f32x4){0.f, 0.f, 0.f, 0.f};
  for (int kb = 0; kb < FEAT; kb += 64) {
    #pragma unroll
    for (int c = 0; c < 4; ++c) {
      int f = c * 256 + tid;
      int row = f >> 3, s = f & 7;
      int sc = (s ^ (row & 7)) << 3;
      gload16(Ag + (size_t)row * FEAT + kb + sc, Als + ((c * 256 + wid * 64) << 3));
      gload16(Bg + (size_t)row * FEAT + kb + sc, Bls + ((c * 256 + wid * 64) << 3));
    }
    __syncthreads();
    #pragma unroll
    for (int ks = 0; ks < 2; ++ks) {
      bf16x8 af[4], bfr[4];
      #pragma unroll
      for (int m = 0; m < 4; ++m) {
        int row = wr * 64 + m * 16 + (lane & 15);
        int kq = ks * 32 + (lane >> 4) * 8;
        int idx = (row * 64 + kq) ^ ((row & 7) << 3);
        af[m] = *(const bf16x8*)(&Als[idx]);
      }
      #pragma unroll
      for (int n = 0; n < 4; ++n) {
        int row = wc * 64 + n * 16 + (lane & 15);
        int kq = ks * 32 + (lane >> 4) * 8;
        int idx = (row * 64 + kq) ^ ((row & 7) << 3);
        bfr[n] = *(const bf16x8*)(&Bls[idx]);
      }
      #pragma unroll
      for (int m = 0; m < 4; ++m)
        #pragma unroll
        for (int n = 0; n < 4; ++n)
          acc[m][n] = __builtin_amdgcn_mfma_f32_16x16x32_bf16(af[m], bfr[n], acc[m][n], 0, 0, 0);
    }
    __syncthreads();
  }
  const float SC = 0.04419417382415922f;   // sqrt(2/1024)
  float rbl[4];
  #pragma unroll
  for (int n = 0; n < 4; ++n) rbl[n] = rb[i0 + wc * 64 + n * 16 + (lane & 15)];
  #pragma unroll
  for (int m = 0; m < 4; ++m) {
    #pragma unroll
    for (int n = 0; n < 4; ++n) {
      #pragma unroll
      for (int r = 0; r < 4; ++r) {
        int lb = wr * 64 + m * 16 + (lane >> 4) * 4 + r;
        int li = wc * 64 + n * 16 + (lane & 15);
        float proj = 2.0f * (acc[m][n][r] + rbl[n]);
        u16 bv = (u16)f2bf(SC * cosf(proj));
        phiB[(size_t)(b0 + lb) * NIND + i0 + li] = bv;
        int idx = (li * 128 + lb) ^ ((li & 7) << 3);
        sh[idx] = bv;
      }
    }
  }
  __syncthreads();
  #pragma unroll
  for (int t = 0; t < 8; ++t) {
    int f = t * 256 + tid;             // 2048 uint4-slots over 128x128 u16
    int li = f >> 4, c8 = (f & 15) << 3;
    int idx = (li * 128 + c8) ^ ((li & 7) << 3);
    uint4 v = *(const uint4*)(&sh[idx]);
    *(uint4*)(phiTB + (size_t)(i0 + li) * BATCH + b0 + c8) = v;
  }
}

// K2: logits from phiB (bf16), 16 batch rows per block, thread = (row, class)
__global__ __launch_bounds__(256) void logits_kernel(
    const u16* __restrict__ phiB, const float* __restrict__ bw,
    const float* __restrict__ bbias, float* __restrict__ out,
    float* __restrict__ wmat)
{
  __shared__ float ph[16][132];
  __shared__ float bwl[16][132];
  __shared__ float lg[16][17];
  const int b0 = blockIdx.x * 16;
  const int tid = threadIdx.x;
  const int bl = tid & 15, kq = tid >> 4;
  float acc = 0.f;
  for (int kb = 0; kb < NIND; kb += 128) {
    {
      int row = tid >> 4, c8 = (tid & 15) << 3;
      uint4 v = *(const uint4*)(phiB + (size_t)(b0 + row) * NIND + kb + c8);
      const unsigned* u = (const unsigned*)&v;
      #pragma unroll
      for (int j = 0; j < 4; ++j) {
        ph[row][c8 + 2*j]     = bflo(u[j]);
        ph[row][c8 + 2*j + 1] = bfhi(u[j]);
      }
    }
    #pragma unroll
    for (int t = 0; t < 2; ++t) {
      int f = t * 256 + tid;
      int row = f >> 5, c4 = (f & 31) << 2;
      *(float4*)(&bwl[row][c4]) = *(const float4*)(bw + (size_t)row * NIND + kb + c4);
    }
    __syncthreads();
    #pragma unroll 8
    for (int q = 0; q < 128; q += 4) {
      float4 a = *(const float4*)(&ph[bl][q]);
      float4 b4 = *(const float4*)(&bwl[kq][q]);
      acc += a.x*b4.x + a.y*b4.y + a.z*b4.z + a.w*b4.w;
    }
    __syncthreads();
  }
  float v = acc + bbias[kq];
  lg[bl][kq] = v;
  out[(size_t)(b0 + bl) * NCLS + kq] = v;
  __syncthreads();
  if (tid < 16) {
    float mx = -1e30f;
    #pragma unroll
    for (int k = 0; k < 16; ++k) mx = fmaxf(mx, lg[tid][k]);
    float s = 0.f, ex[16];
    #pragma unroll
    for (int k = 0; k < 16; ++k) { ex[k] = expf(lg[tid][k] - mx); s += ex[k]; }
    float inv = 1.0f / s;
    #pragma unroll
    for (int k = 0; k < 16; ++k) {
      float p = ex[k] * inv;
      wmat[(size_t)k * BATCH + b0 + tid] = p * (1.0f - p);
    }
  }
}

// K2b: phiW[k][i][b] = bf16(wmat[k][b] * phi[i][b])  (from bf16 phiTB)
__global__ __launch_bounds__(256) void scalew_kernel(
    const u16* __restrict__ phiTB, const float* __restrict__ wmat,
    u16* __restrict__ phiW)
{
  const int k = blockIdx.y;
  size_t flat = ((size_t)blockIdx.x * 256 + threadIdx.x) * 8;
  int b = (int)(flat & 2047);
  uint4 pv = *(const uint4*)(phiTB + flat);
  float4 w0 = *(const float4*)(wmat + (size_t)k * BATCH + b);
  float4 w1 = *(const float4*)(wmat + (size_t)k * BATCH + b + 4);
  float wv[8] = {w0.x, w0.y, w0.z, w0.w, w1.x, w1.y, w1.z, w1.w};
  *(uint4*)(phiW + (size_t)k * NIND * BATCH + flat) = scale8(pv, wv);
}

// K3 v9: MFMA bf16 gram -> Pb bf16, 256x128 tiles (512 threads, 8 waves 4x2;
// per-wave 64x64 sub-tile identical to the proven 128x128 version, but 25%
// less traffic per output -- R22-validated transformation). XCD = tj.
// Epilogue emits per-row |P| partials (Gershgorin fold): slice (k, tj, wc)
// still has a unique writer per row (ti = row>>8, wr = (row>>6)&3).
__global__ __launch_bounds__(512) void gram_kernel(
    const u16* __restrict__ phiW, const u16* __restrict__ phiTB,
    const float* __restrict__ prec, u16* __restrict__ Pb,
    float* __restrict__ rowAbs)
{
  __shared__ u16 Als[256 * 64];   // 32KB
  __shared__ u16 Bls[128 * 64];   // 16KB
  const int tj = blockIdx.x & 7, ti = blockIdx.x >> 3;   // XCD = tj
  const int k = blockIdx.y;
  const int i0 = ti * 256, j0 = tj * 128;
  const int tid = threadIdx.x;
  const int wid = tid >> 6, lane = tid & 63;
  const int wr = wid >> 1, wc = wid & 1;    // wr in [0,4), wc in [0,2)
  const u16* Ag = phiW + (size_t)k * NIND * BATCH + (size_t)i0 * BATCH;
  const u16* Bg = phiTB + (size_t)j0 * BATCH;
  f32x4 acc[4][4];
  #pragma unroll
  for (int m = 0; m < 4; ++m)
    #pragma unroll
    for (int n = 0; n < 4; ++n) acc[m][n] = (f32x4){0.f, 0.f, 0.f, 0.f};
  for (int b0 = 0; b0 < BATCH; b0 += 64) {
    #pragma unroll
    for (int c = 0; c < 4; ++c) {        // A: 2048 slots (256 rows x 8 chunks)
      int f = c * 512 + tid;
      int row = f >> 3, s = f & 7;
      int sc = (s ^ (row & 7)) << 3;
      gload16(Ag + (size_t)row * BATCH + b0 + sc, Als + ((c * 512 + wid * 64) << 3));
    }
    #pragma unroll
    for (int c = 0; c < 2; ++c) {        // B: 1024 slots (128 rows x 8 chunks)
      int f = c * 512 + tid;
      int row = f >> 3, s = f & 7;
      int sc = (s ^ (row & 7)) << 3;
      gload16(Bg + (size_t)row * BATCH + b0 + sc, Bls + ((c * 512 + wid * 64) << 3));
    }
    __syncthreads();
    #pragma unroll
    for (int ks = 0; ks < 2; ++ks) {
      bf16x8 af[4], bfr[4];
      #pragma unroll
      for (int m = 0; m < 4; ++m) {
        int row = wr * 64 + m * 16 + (lane & 15);      // [0,256)
        int kb = ks * 32 + (lane >> 4) * 8;
        int idx = (row * 64 + kb) ^ ((row & 7) << 3);
        af[m] = *(const bf16x8*)(&Als[idx]);
      }
      #pragma unroll
      for (int n = 0; n < 4; ++n) {
        int row = wc * 64 + n * 16 + (lane & 15);      // [0,128)
        int kb = ks * 32 + (lane >> 4) * 8;
        int idx = (row * 64 + kb) ^ ((row & 7) << 3);
        bfr[n] = *(const bf16x8*)(&Bls[idx]);
      }
      #pragma unroll
      for (int m = 0; m < 4; ++m)
        #pragma unroll
        for (int n = 0; n < 4; ++n)
          acc[m][n] = __builtin_amdgcn_mfma_f32_16x16x32_bf16(af[m], bfr[n], acc[m][n], 0, 0, 0);
    }
    __syncthreads();
  }
  const size_t kb2 = (size_t)k * NIND * NIND;
  float sabs[4][4];
  #pragma unroll
  for (int m = 0; m < 4; ++m)
    #pragma unroll
    for (int r = 0; r < 4; ++r) sabs[m][r] = 0.f;
  #pragma unroll
  for (int m = 0; m < 4; ++m) {
    #pragma unroll
    for (int n = 0; n < 4; ++n) {
      #pragma unroll
      for (int r = 0; r < 4; ++r) {
        int gi = i0 + wr * 64 + m * 16 + (lane >> 4) * 4 + r;
        int gj = j0 + wc * 64 + n * 16 + (lane & 15);
        size_t idx = kb2 + (size_t)gi * NIND + gj;
        float v = acc[m][n][r] + prec[idx];
        u16 bv = (u16)f2bf(v);
        Pb[idx] = bv;
        sabs[m][r] += fabsf(__uint_as_float((unsigned)bv << 16));
      }
    }
  }
  // butterfly over the 16 column-lanes (gi depends only on lane>>4) -> row sums
  float* rp = rowAbs + ((size_t)k * 16 + tj * 2 + wc) * NIND + i0;
  #pragma unroll
  for (int m = 0; m < 4; ++m) {
    #pragma unroll
    for (int r = 0; r < 4; ++r) {
      float s = sabs[m][r];
      s += __shfl_xor(s, 1);
      s += __shfl_xor(s, 2);
      s += __shfl_xor(s, 4);
      s += __shfl_xor(s, 8);
      if ((lane & 15) == 0)
        rp[wr * 64 + m * 16 + (lane >> 4) * 4 + r] = s;
    }
  }
}

// K4: gersh2 -- G[k] = max_row sum over the 16 rowAbs slices (1MB total read)
__global__ __launch_bounds__(256) void gersh2_kernel(
    const float* __restrict__ rowAbs, unsigned* __restrict__ gmax)
{
  __shared__ float red[256];
  const int k = blockIdx.x, tid = threadIdx.x;
  const float* base = rowAbs + (size_t)k * 16 * NIND;
  float mx = 0.f;
  for (int row = tid; row < NIND; row += 256) {
    float s = 0.f;
    #pragma unroll
    for (int sl = 0; sl < 16; ++sl) s += base[(size_t)sl * NIND + row];
    mx = fmaxf(mx, s);
  }
  red[tid] = mx;
  __syncthreads();
  for (int o = 128; o > 0; o >>= 1) {
    if (tid < o) red[tid] = fmaxf(red[tid], red[tid + o]);
    __syncthreads();
  }
  if (tid == 0) gmax[k] = __float_as_uint(red[0]);
}

// K6: 256x128-tile GEMM C = A (*) B^T (512 threads, 8 waves 4x2). Epilogue:
// mode 0: C = acc
// mode 1: C = 2*Xadd - acc
// mode 2: C = a3*acc + a2*Xadd + a1*Pex + a0*I  (deg-3 Chebyshev init)
// mode 3: mode 1 + double 128-tile-off-diagonal entries (vgemm contract)
__global__ __launch_bounds__(512) void ntgemm_kernel(
    const u16* __restrict__ A, const u16* __restrict__ B,
    const u16* __restrict__ Xadd, const u16* __restrict__ Pex,
    const unsigned* __restrict__ gmax, u16* __restrict__ C, int mode)
{
  __shared__ u16 Als[256 * 64];   // 32KB
  __shared__ u16 Bls[128 * 64];   // 16KB
  const int k = blockIdx.y;
  const int tj = blockIdx.x & 7, ti = blockIdx.x >> 3;   // XCD = tj
  const int i0 = ti * 256, j0 = tj * 128;
  const int tid = threadIdx.x;
  const int wid = tid >> 6, lane = tid & 63;
  const int wr = wid >> 1, wc = wid & 1;    // wr in [0,4), wc in [0,2)
  const size_t mb = (size_t)k * NIND * NIND;
  const u16* Ag = A + mb + (size_t)i0 * NIND;
  const u16* Bg = B + mb + (size_t)j0 * NIND;
  f32x4 acc[4][4];
  #pragma unroll
  for (int m = 0; m < 4; ++m)
    #pragma unroll
    for (int n = 0; n < 4; ++n) acc[m][n] = (f32x4){0.f, 0.f, 0.f, 0.f};
  for (int kb = 0; kb < NIND; kb += 64) {
    #pragma unroll
    for (int c = 0; c < 4; ++c) {        // A: 2048 slots (256 rows x 8 chunks)
      int f = c * 512 + tid;
      int row = f >> 3, s = f & 7;
      int sc = (s ^ (row & 7)) << 3;
      gload16(Ag + (size_t)row * NIND + kb + sc, Als + ((c * 512 + wid * 64) << 3));
    }
    #pragma unroll
    for (int c = 0; c < 2; ++c) {        // B: 1024 slots (128 rows x 8 chunks)
      int f = c * 512 + tid;
      int row = f >> 3, s = f & 7;
      int sc = (s ^ (row & 7)) << 3;
      gload16(Bg + (size_t)row * NIND + kb + sc, Bls + ((c * 512 + wid * 64) << 3));
    }
    __syncthreads();
    #pragma unroll
    for (int ks = 0; ks < 2; ++ks) {
      bf16x8 af[4], bfr[4];
      #pragma unroll
      for (int m = 0; m < 4; ++m) {
        int row = wr * 64 + m * 16 + (lane & 15);      // [0,256)
        int kq = ks * 32 + (lane >> 4) * 8;
        int idx = (row * 64 + kq) ^ ((row & 7) << 3);
        af[m] = *(const bf16x8*)(&Als[idx]);
      }
      #pragma unroll
      for (int n = 0; n < 4; ++n) {
        int row = wc * 64 + n * 16 + (lane & 15);      // [0,128)
        int kq = ks * 32 + (lane >> 4) * 8;
        int idx = (row * 64 + kq) ^ ((row & 7) << 3);
        bfr[n] = *(const bf16x8*)(&Bls[idx]);
      }
      #pragma unroll
      for (int m = 0; m < 4; ++m)
        #pragma unroll
        for (int n = 0; n < 4; ++n)
          acc[m][n] = __builtin_amdgcn_mfma_f32_16x16x32_bf16(af[m], bfr[n], acc[m][n], 0, 0, 0);
    }
    __syncthreads();
  }
  float a0 = 0.f, a1 = 0.f, a2 = 0.f, a3 = 0.f;
  if (mode == 2) {
    float G = __uint_as_float(gmax[k]) * 1.001f + 0.01f;
    if (G < 1.05f) G = 1.05f;
    float s = 1.0f + G, dd = G - 1.0f;
    float s2 = s * s, d2 = dd * dd;
    float D = 8.0f * s2 * s2 - 8.0f * d2 * s2 + d2 * d2;
    a3 = -128.0f / D;
    a2 = 256.0f * s / D;
    a1 = -(192.0f * s2 - 32.0f * d2) / D;
    a0 = (64.0f * s2 * s - 32.0f * d2 * s) / D;
  }
  #pragma unroll
  for (int m = 0; m < 4; ++m) {
    #pragma unroll
    for (int n = 0; n < 4; ++n) {
      #pragma unroll
      for (int r = 0; r < 4; ++r) {
        int gi = i0 + wr * 64 + m * 16 + (lane >> 4) * 4 + r;
        int gj = j0 + wc * 64 + n * 16 + (lane & 15);
        size_t idx = mb + (size_t)gi * NIND + gj;
        float v = acc[m][n][r];
        if (mode == 1 || mode == 3) {
          v = 2.0f * bflo((unsigned)Xadd[idx]) - v;
          if (mode == 3 && (gi >> 7) != (gj >> 7)) v *= 2.0f;
        } else if (mode == 2) {
          v = a3 * v + a2 * bflo((unsigned)Xadd[idx]) + a1 * bflo((unsigned)Pex[idx]);
          if (gi == gj) v += a0;
        }
        C[idx] = (u16)f2bf(v);
      }
    }
  }
}

// K7: balanced triangular variance GEMM. Block = (btile, pr); sequentially
// computes TWO row-blocks It0=pr and It1=7-pr, each with triangular K from
// It*128: (8-pr) + (1+pr) = 9 K-tiles per block, uniform. M tile-off-diag
// pre-doubled (mode 3) so triangular K gives phi^T sym(M) phi exactly.
__global__ __launch_bounds__(256) void vgemm_kernel(
    const u16* __restrict__ phiB, const u16* __restrict__ M,
    float* __restrict__ partial)
{
  __shared__ u16 Als[128 * 64];
  __shared__ u16 Bls[128 * 64];
  __shared__ float red[128][33];
  const int btile = blockIdx.x >> 2, pr = blockIdx.x & 3;
  const int k = blockIdx.y;
  const int b0 = btile * 128;
  const int tid = threadIdx.x;
  const int wid = tid >> 6, lane = tid & 63;
  const int wr = wid >> 1, wc = wid & 1;
  const int q = lane >> 4, l15 = lane & 15;
  const u16* Ag = phiB + (size_t)b0 * NIND;
  #pragma unroll
  for (int ph = 0; ph < 2; ++ph) {
    const int It = ph ? (7 - pr) : pr;
    const int i0 = It * 128;
    const u16* Bg = M + (size_t)k * NIND * NIND + (size_t)i0 * NIND;
    f32x4 acc[4][4];
    #pragma unroll
    for (int m = 0; m < 4; ++m)
      #pragma unroll
      for (int n = 0; n < 4; ++n) acc[m][n] = (f32x4){0.f, 0.f, 0.f, 0.f};
    for (int kb = i0; kb < NIND; kb += 64) {
      #pragma unroll
      for (int c = 0; c < 4; ++c) {
        int f = c * 256 + tid;
        int row = f >> 3, s = f & 7;
        int sc = (s ^ (row & 7)) << 3;
        gload16(Ag + (size_t)row * NIND + kb + sc, Als + ((c * 256 + wid * 64) << 3));
        gload16(Bg + (size_t)row * NIND + kb + sc, Bls + ((c * 256 + wid * 64) << 3));
      }
      __syncthreads();
      #pragma unroll
      for (int ks = 0; ks < 2; ++ks) {
        bf16x8 af[4], bfr[4];
        #pragma unroll
        for (int m = 0; m < 4; ++m) {
          int row = wr * 64 + m * 16 + l15;
          int kq = ks * 32 + q * 8;
          int idx = (row * 64 + kq) ^ ((row & 7) << 3);
          af[m] = *(const bf16x8*)(&Als[idx]);
        }
        #pragma unroll
        for (int n = 0; n < 4; ++n) {
          int row = wc * 64 + n * 16 + l15;
          int kq = ks * 32 + q * 8;
          int idx = (row * 64 + kq) ^ ((row & 7) << 3);
          bfr[n] = *(const bf16x8*)(&Bls[idx]);
        }
        #pragma unroll
        for (int m = 0; m < 4; ++m)
          #pragma unroll
          for (int n = 0; n < 4; ++n)
            acc[m][n] = __builtin_amdgcn_mfma_f32_16x16x32_bf16(af[m], bfr[n], acc[m][n], 0, 0, 0);
      }
      __syncthreads();
    }
    float vs[4][4] = {};
    #pragma unroll
    for (int m = 0; m < 4; ++m) {
      #pragma unroll
      for (int r = 0; r < 4; ++r) {
        int gb = b0 + wr * 64 + m * 16 + q * 4 + r;
        #pragma unroll
        for (int n = 0; n < 4; ++n) {
          int gi = i0 + wc * 64 + n * 16 + l15;
          float pv = bflo((unsigned)phiB[(size_t)gb * NIND + gi]);
          vs[m][r] += acc[m][n][r] * pv;
        }
      }
    }
    #pragma unroll
    for (int m = 0; m < 4; ++m)
      #pragma unroll
      for (int r = 0; r < 4; ++r)
        red[wr * 64 + m * 16 + q * 4 + r][wc * 16 + l15] = vs[m][r];
    __syncthreads();
    if (tid < 128) {
      float s = 0.f;
      #pragma unroll
      for (int t = 0; t < 32; ++t) s += red[tid][t];
      partial[((size_t)It * NCLS + k) * BATCH + b0 + tid] = s;
    }
    __syncthreads();
  }
}

// K8: out variances[b][k] = sum_It partial[It][k][b]
__global__ __launch_bounds__(256) void reduce_kernel(
    const float* __restrict__ partial, float* __restrict__ out)
{
  int t = blockIdx.x * 256 + threadIdx.x;
  int k = t >> 11, b = t & 2047;
  float s = 0.f;
  #pragma unroll
  for (int It = 0; It < 8; ++It)
    s += partial[((size_t)It * NCLS + k) * BATCH + b];
  out[(size_t)BATCH * NCLS + (size_t)b * NCLS + k] = s;
}

extern "C" void kernel_launch(void* const* d_in, const int* in_sizes, int n_in,
                              void* d_out, int out_size, void* d_ws, size_t ws_size,
                              hipStream_t stream)
{
  (void)in_sizes; (void)n_in; (void)ws_size; (void)out_size;
  const float* x   = (const float*)d_in[0];
  const float* rw  = (const float*)d_in[1];
  const float* rb  = (const float*)d_in[2];
  const float* bw  = (const float*)d_in[3];
  const float* bb  = (const float*)d_in[4];
  const float* prc = (const float*)d_in[5];
  float* out = (float*)d_out;
  char* ws = (char*)d_ws;
  size_t off = 0;
  auto alloc = [&](size_t bytes) -> void* {
    void* p = ws + off;
    off = (off + bytes + 255) & ~(size_t)255;
    return p;
  };
  const size_t MSZ = (size_t)NCLS * NIND * NIND * 2;   // 32MB bf16 matrix
  u16*   xB     = (u16*)  alloc((size_t)BATCH * FEAT * 2);
  u16*   rwT    = (u16*)  alloc((size_t)NIND * FEAT * 2);
  u16*   phiB   = (u16*)  alloc((size_t)BATCH * NIND * 2);
  u16*   phiTB  = (u16*)  alloc((size_t)NIND * BATCH * 2);
  float* wmat   = (float*)alloc((size_t)NCLS * BATCH * 4);
  u16*   Pb     = (u16*)  alloc(MSZ);
  unsigned* gbound = (unsigned*)alloc((size_t)NCLS * 4);
  float* rowAbs = (float*)alloc((size_t)NCLS * 16 * NIND * 4);   // 1MB
  float* partial = (float*)alloc((size_t)8 * NCLS * BATCH * 4);
  u16*   Xa     = (u16*)alloc(MSZ);
  u16*   B2     = (u16*)alloc(MSZ);
  u16*   BY     = (u16*)alloc(MSZ);
  // phiW (64MB) aliases Xa+B2 (contiguous): dead before G2 writes Xa.
  u16*   phiW   = Xa;

  xcast_kernel<<<dim3(BATCH * FEAT / 2048), 256, 0, stream>>>(x, xB);
  rwt_kernel<<<dim3(FEAT / 64, NIND / 64), 256, 0, stream>>>(rw, rwT);
  phimm_kernel<<<dim3(BATCH / 128, NIND / 128), 256, 0, stream>>>(xB, rwT, rb, phiB, phiTB);
  logits_kernel<<<dim3(BATCH / 16), 256, 0, stream>>>(phiB, bw, bb, out, wmat);
  scalew_kernel<<<dim3(1024, NCLS), 256, 0, stream>>>(phiTB, wmat, phiW);
  gram_kernel<<<dim3(32, NCLS), 512, 0, stream>>>(phiW, phiTB, prc, Pb, rowAbs);
  gersh2_kernel<<<dim3(NCLS), 256, 0, stream>>>(rowAbs, gbound);
  const dim3 gg(32, NCLS);
  // G1: BY = P^2
  ntgemm_kernel<<<gg, 512, 0, stream>>>(Pb, Pb, (u16*)nullptr, (u16*)nullptr,
                                        (unsigned*)nullptr, BY, 0);
  // G2: Xa = a3*P^3 + a2*P^2 + a1*P + a0*I  (cheb-3 fused into the P^3 GEMM)
  ntgemm_kernel<<<gg, 512, 0, stream>>>(BY, Pb, BY, Pb, gbound, Xa, 2);
  // G3+G4: one Newton iteration: BY = Xa*P ; B2 = (2*Xa - Xa*BY^T) with
  // 128-tile-off-diagonal entries doubled (mode 3) for the triangular vgemm.
  ntgemm_kernel<<<gg, 512, 0, stream>>>(Xa, Pb, (u16*)nullptr, (u16*)nullptr,
                                        (unsigned*)nullptr, BY, 0);
  ntgemm_kernel<<<gg, 512, 0, stream>>>(Xa, BY, Xa, (u16*)nullptr,
                                        (unsigned*)nullptr, B2, 3);
  // variances: var_b = phi^T sym(M) phi via balanced triangular K (9 tiles/block)
  vgemm_kernel<<<dim3(64, NCLS), 256, 0, stream>>>(phiB, B2, partial);
  reduce_kernel<<<dim3(128), 256, 0, stream>>>(partial, out);
}